// Round 2
// baseline (668.959 us; speedup 1.0000x reference)
//
#include <hip/hip_runtime.h>

// Problem constants
#define Tn   1024
#define Bn   4
#define En   1024
#define Hn   16
#define HIDn 1024
#define SIGn 64
#define Mn   (Tn * Bn)   // 4096 rows when x viewed as (T*B, E)

typedef short  s8x8  __attribute__((ext_vector_type(8)));   // 8 bf16 (4 VGPRs)
typedef float  f32x4 __attribute__((ext_vector_type(4)));   // MFMA acc

__device__ __forceinline__ float bf2f(unsigned short u) {
    return __uint_as_float(((unsigned int)u) << 16);
}
__device__ __forceinline__ unsigned short f2bf(float f) {
    unsigned int x = __float_as_uint(f);
    unsigned int r = (x + 0x7fffu + ((x >> 16) & 1u)) >> 16;   // RNE
    return (unsigned short)r;
}

// ---------------------------------------------------------------------------
// fp32 -> bf16 cast, 8 elems/thread
// ---------------------------------------------------------------------------
__global__ __launch_bounds__(256) void cast_bf16(
    const float* __restrict__ s, unsigned short* __restrict__ d, int n8)
{
    int i = blockIdx.x * 256 + threadIdx.x;
    if (i >= n8) return;
    const float4* p = (const float4*)(s + (size_t)i * 8);
    float4 a = p[0], b = p[1];
    s8x8 o;
    o[0] = (short)f2bf(a.x); o[1] = (short)f2bf(a.y);
    o[2] = (short)f2bf(a.z); o[3] = (short)f2bf(a.w);
    o[4] = (short)f2bf(b.x); o[5] = (short)f2bf(b.y);
    o[6] = (short)f2bf(b.z); o[7] = (short)f2bf(b.w);
    *(s8x8*)(d + (size_t)i * 8) = o;
}

// ---------------------------------------------------------------------------
// bf16 MFMA GEMM:  C[m][n] = act((sum_k A[m][k]*W[n][k] + bias[n]) * scale)
// A: M x K (fp32 if A_BF16=0, bf16 if 1).  W: N x K bf16 (pre-cast).
// 128x128 tile, BK=32, 256 thr = 4 waves in 2x2, 4x4 frags of 16x16x32/wave.
// C/D layout (verified m89/m91): col = lane&15, row = (lane>>4)*4 + reg.
// LDS row stride 40 shorts (80 B, 16B-aligned rows).
// ---------------------------------------------------------------------------
template <int A_BF16, int RELU, int OUT_BF16>
__global__ __launch_bounds__(256) void mfma_gemm(
    const void* __restrict__ Ap, const unsigned short* __restrict__ Wb,
    const float* __restrict__ bias, void* __restrict__ Cp,
    int M, int N, int K, float scale)
{
    __shared__ short As[128 * 40];
    __shared__ short Bs[128 * 40];
    const int tid  = threadIdx.x;
    const int wave = tid >> 6;
    const int lane = tid & 63;
    const int ln15 = lane & 15;
    const int kq   = lane >> 4;          // 0..3
    const int wr   = wave >> 1;          // wave row 0..1
    const int wc   = wave & 1;           // wave col 0..1
    const size_t rowA0 = (size_t)blockIdx.y * 128;
    const size_t rowB0 = (size_t)blockIdx.x * 128;

    const int srow = tid >> 1;           // staging row 0..127
    const int scol = (tid & 1) * 16;     // staging col 0 or 16

    f32x4 acc[4][4];
#pragma unroll
    for (int m = 0; m < 4; m++)
#pragma unroll
        for (int n = 0; n < 4; n++) acc[m][n] = (f32x4){0.f, 0.f, 0.f, 0.f};

    const float*          Af = (const float*)Ap;
    const unsigned short* Ab = (const unsigned short*)Ap;

    for (int k0 = 0; k0 < K; k0 += 32) {
        // ---- stage A (128x32) ----
        s8x8 v0, v1;
        if (A_BF16) {
            const s8x8* src = (const s8x8*)(Ab + (rowA0 + srow) * K + k0 + scol);
            v0 = src[0]; v1 = src[1];
        } else {
            const float4* src = (const float4*)(Af + (rowA0 + srow) * K + k0 + scol);
            float4 a = src[0], b = src[1], c = src[2], d = src[3];
            v0[0] = (short)f2bf(a.x); v0[1] = (short)f2bf(a.y);
            v0[2] = (short)f2bf(a.z); v0[3] = (short)f2bf(a.w);
            v0[4] = (short)f2bf(b.x); v0[5] = (short)f2bf(b.y);
            v0[6] = (short)f2bf(b.z); v0[7] = (short)f2bf(b.w);
            v1[0] = (short)f2bf(c.x); v1[1] = (short)f2bf(c.y);
            v1[2] = (short)f2bf(c.z); v1[3] = (short)f2bf(c.w);
            v1[4] = (short)f2bf(d.x); v1[5] = (short)f2bf(d.y);
            v1[6] = (short)f2bf(d.z); v1[7] = (short)f2bf(d.w);
        }
        *(s8x8*)&As[srow * 40 + scol]     = v0;
        *(s8x8*)&As[srow * 40 + scol + 8] = v1;
        // ---- stage B = W tile (128x32 bf16) ----
        {
            const s8x8* src = (const s8x8*)(Wb + (rowB0 + srow) * K + k0 + scol);
            *(s8x8*)&Bs[srow * 40 + scol]     = src[0];
            *(s8x8*)&Bs[srow * 40 + scol + 8] = src[1];
        }
        __syncthreads();

        s8x8 af[4], bf[4];
#pragma unroll
        for (int m = 0; m < 4; m++)
            af[m] = *(const s8x8*)&As[(wr * 64 + m * 16 + ln15) * 40 + kq * 8];
#pragma unroll
        for (int n = 0; n < 4; n++)
            bf[n] = *(const s8x8*)&Bs[(wc * 64 + n * 16 + ln15) * 40 + kq * 8];
#pragma unroll
        for (int m = 0; m < 4; m++)
#pragma unroll
            for (int n = 0; n < 4; n++)
                acc[m][n] = __builtin_amdgcn_mfma_f32_16x16x32_bf16(
                    af[m], bf[n], acc[m][n], 0, 0, 0);
        __syncthreads();
    }

    // ---- epilogue ----
    float bcol[4];
#pragma unroll
    for (int n = 0; n < 4; n++)
        bcol[n] = bias[rowB0 + wc * 64 + n * 16 + ln15];
#pragma unroll
    for (int m = 0; m < 4; m++) {
        size_t gr0 = rowA0 + wr * 64 + m * 16 + kq * 4;
#pragma unroll
        for (int n = 0; n < 4; n++) {
            size_t gc = rowB0 + wc * 64 + n * 16 + ln15;
#pragma unroll
            for (int j = 0; j < 4; j++) {
                float vv = (acc[m][n][j] + bcol[n]) * scale;
                if (RELU) vv = fmaxf(vv, 0.f);
                if (OUT_BF16)
                    ((unsigned short*)Cp)[(gr0 + j) * N + gc] = f2bf(vv);
                else
                    ((float*)Cp)[(gr0 + j) * N + gc] = vv;
            }
        }
    }
}

// ---------------------------------------------------------------------------
// t2 = t1(bf16) @ W2^T + b2   (M=4096, N=64, K=1024), fp32 out. Scalar VALU.
// ---------------------------------------------------------------------------
__global__ __launch_bounds__(256) void gemm_t2(
    const unsigned short* __restrict__ A, const float* __restrict__ W,
    const float* __restrict__ b2, float* __restrict__ C)
{
    __shared__ float As[64][33];
    __shared__ float Ws[64][33];
    const int tid = threadIdx.x;
    const int tx = tid & 15;
    const int tg = tid >> 4;
    const int bm = blockIdx.x;
    const unsigned short* Ab = A + (size_t)bm * 64 * HIDn;

    float acc[4][4] = {{0.f}};

    for (int k0 = 0; k0 < HIDn; k0 += 32) {
        {
            int row = tid >> 2;
            int col = (tid & 3) * 8;
            s8x8 s = *(const s8x8*)(Ab + (size_t)row * HIDn + k0 + col);
#pragma unroll
            for (int i = 0; i < 8; i++)
                As[row][col + i] = bf2f((unsigned short)s[i]);
        }
#pragma unroll
        for (int i = 0; i < 2; i++) {
            int idx = tid + i * 256;
            int row = idx >> 3;
            int col = (idx & 7) * 4;
            float4 vw = *(const float4*)(W + (size_t)row * HIDn + k0 + col);
            Ws[row][col + 0] = vw.x; Ws[row][col + 1] = vw.y;
            Ws[row][col + 2] = vw.z; Ws[row][col + 3] = vw.w;
        }
        __syncthreads();
#pragma unroll 8
        for (int kk = 0; kk < 32; kk++) {
            float a[4], w[4];
#pragma unroll
            for (int i = 0; i < 4; i++) a[i] = As[tg * 4 + i][kk];
#pragma unroll
            for (int j = 0; j < 4; j++) w[j] = Ws[tx * 4 + j][kk];
#pragma unroll
            for (int i = 0; i < 4; i++)
#pragma unroll
                for (int j = 0; j < 4; j++)
                    acc[i][j] += a[i] * w[j];
        }
        __syncthreads();
    }
#pragma unroll
    for (int i = 0; i < 4; i++)
#pragma unroll
        for (int j = 0; j < 4; j++)
            C[(size_t)(bm * 64 + tg * 4 + i) * SIGn + tx * 4 + j] =
                acc[i][j] + b2[tx * 4 + j];
}

// ---------------------------------------------------------------------------
// Gate: logits = t2 @ hs^T (K=64, H=16), softmax over heads. One row/thread.
// ---------------------------------------------------------------------------
__global__ __launch_bounds__(256) void gate_kernel(
    const float* __restrict__ t2, const float* __restrict__ hs,
    float* __restrict__ gate)
{
    __shared__ float hss[Hn][SIGn];
    const int tid = threadIdx.x;
#pragma unroll
    for (int i = 0; i < 4; i++) {
        int idx = tid + i * 256;
        hss[idx >> 6][idx & 63] = hs[idx];
    }
    __syncthreads();

    const int m = blockIdx.x * 256 + tid;
    const float* row = t2 + (size_t)m * SIGn;
    float logits[Hn];
    float mx = -1e30f;
#pragma unroll
    for (int h = 0; h < Hn; h++) {
        float s = 0.f;
#pragma unroll 8
        for (int s0 = 0; s0 < SIGn; s0++) s += row[s0] * hss[h][s0];
        logits[h] = s;
        mx = fmaxf(mx, s);
    }
    float sum = 0.f;
#pragma unroll
    for (int h = 0; h < Hn; h++) {
        logits[h] = __expf(logits[h] - mx);
        sum += logits[h];
    }
    float inv = 1.f / sum;
#pragma unroll
    for (int h = 0; h < Hn; h++) gate[(size_t)m * Hn + h] = logits[h] * inv;
}

// ---------------------------------------------------------------------------
// Flash attention, fp32 compute, bf16 I/O. Block = (b,h,64-row Q tile).
// q pre-scaled by d^-0.5. Gate folded into the O write (bf16, (m,e) layout).
// ---------------------------------------------------------------------------
__global__ __launch_bounds__(256) void attn_kernel(
    const unsigned short* __restrict__ q, const unsigned short* __restrict__ k,
    const unsigned short* __restrict__ v, const float* __restrict__ gate,
    unsigned short* __restrict__ o)
{
    __shared__ float Qs[64][65];
    __shared__ float Ks[64][65];
    __shared__ float Vs[64][65];
    __shared__ float Ps[64][65];

    const int tid = threadIdx.x;
    const int bh = blockIdx.x;
    const int b = bh >> 4;
    const int h = bh & 15;
    const int qt = blockIdx.y;
    const int tx = tid & 15;
    const int tg = tid >> 4;

    {
        int r = tid >> 2;
        int cq = (tid & 3) * 16;
        const unsigned short* src =
            q + ((size_t)(qt * 64 + r) * Bn + b) * En + h * 64 + cq;
        s8x8 s0 = *(const s8x8*)(src);
        s8x8 s1 = *(const s8x8*)(src + 8);
#pragma unroll
        for (int i = 0; i < 8; i++) {
            Qs[r][cq + i]     = bf2f((unsigned short)s0[i]);
            Qs[r][cq + 8 + i] = bf2f((unsigned short)s1[i]);
        }
    }

    float mrun[4], lrun[4], O[4][4];
#pragma unroll
    for (int i = 0; i < 4; i++) {
        mrun[i] = -1e30f;
        lrun[i] = 0.f;
#pragma unroll
        for (int j = 0; j < 4; j++) O[i][j] = 0.f;
    }
    __syncthreads();

    for (int s0i = 0; s0i < Tn; s0i += 64) {
        {
            int r = tid >> 2;
            int cq = (tid & 3) * 16;
            const unsigned short* ksrc =
                k + ((size_t)(s0i + r) * Bn + b) * En + h * 64 + cq;
            const unsigned short* vsrc =
                v + ((size_t)(s0i + r) * Bn + b) * En + h * 64 + cq;
            s8x8 ka = *(const s8x8*)(ksrc);
            s8x8 kb = *(const s8x8*)(ksrc + 8);
            s8x8 va = *(const s8x8*)(vsrc);
            s8x8 vb = *(const s8x8*)(vsrc + 8);
#pragma unroll
            for (int i = 0; i < 8; i++) {
                Ks[r][cq + i]     = bf2f((unsigned short)ka[i]);
                Ks[r][cq + 8 + i] = bf2f((unsigned short)kb[i]);
                Vs[r][cq + i]     = bf2f((unsigned short)va[i]);
                Vs[r][cq + 8 + i] = bf2f((unsigned short)vb[i]);
            }
        }
        __syncthreads();

        float S[4][4] = {{0.f}};
#pragma unroll 8
        for (int kk = 0; kk < 64; kk++) {
            float a[4], w[4];
#pragma unroll
            for (int i = 0; i < 4; i++) a[i] = Qs[tg * 4 + i][kk];
#pragma unroll
            for (int j = 0; j < 4; j++) w[j] = Ks[tx * 4 + j][kk];
#pragma unroll
            for (int i = 0; i < 4; i++)
#pragma unroll
                for (int j = 0; j < 4; j++)
                    S[i][j] += a[i] * w[j];
        }

#pragma unroll
        for (int i = 0; i < 4; i++) {
            float lm = fmaxf(fmaxf(S[i][0], S[i][1]), fmaxf(S[i][2], S[i][3]));
            lm = fmaxf(lm, __shfl_xor(lm, 1));
            lm = fmaxf(lm, __shfl_xor(lm, 2));
            lm = fmaxf(lm, __shfl_xor(lm, 4));
            lm = fmaxf(lm, __shfl_xor(lm, 8));
            float mnew = fmaxf(mrun[i], lm);
            float f = __expf(mrun[i] - mnew);
            float ps = 0.f;
#pragma unroll
            for (int j = 0; j < 4; j++) {
                S[i][j] = __expf(S[i][j] - mnew);
                ps += S[i][j];
            }
            ps += __shfl_xor(ps, 1);
            ps += __shfl_xor(ps, 2);
            ps += __shfl_xor(ps, 4);
            ps += __shfl_xor(ps, 8);
            lrun[i] = lrun[i] * f + ps;
            mrun[i] = mnew;
#pragma unroll
            for (int j = 0; j < 4; j++) O[i][j] *= f;
#pragma unroll
            for (int j = 0; j < 4; j++) Ps[tg * 4 + i][tx * 4 + j] = S[i][j];
        }
        __syncthreads();

#pragma unroll 8
        for (int s = 0; s < 64; s++) {
            float p[4], vv[4];
#pragma unroll
            for (int i = 0; i < 4; i++) p[i] = Ps[tg * 4 + i][s];
#pragma unroll
            for (int j = 0; j < 4; j++) vv[j] = Vs[s][tx * 4 + j];
#pragma unroll
            for (int i = 0; i < 4; i++)
#pragma unroll
                for (int j = 0; j < 4; j++)
                    O[i][j] += p[i] * vv[j];
        }
        __syncthreads();
    }

#pragma unroll
    for (int i = 0; i < 4; i++) {
        int t = qt * 64 + tg * 4 + i;
        int m = t * Bn + b;
        float g = gate[(size_t)m * Hn + h] / lrun[i];
#pragma unroll
        for (int j = 0; j < 4; j++)
            o[(size_t)m * En + h * 64 + tx * 4 + j] = f2bf(O[i][j] * g);
    }
}

// ---------------------------------------------------------------------------
// Workspace layout (41.25 MB total — reduced from 65.25 MB):
//   W1b 2MB | Wqb 2MB | Wkb 2MB | Wvb 2MB | t1b 8MB | qb 8MB | kb 8MB |
//   vb 8MB | t2 1MB | gate 0.25MB
//   Aliases (serialized by kernel order): Wob <- W1b slot, ob <- t1b slot.
// ---------------------------------------------------------------------------
extern "C" void kernel_launch(void* const* d_in, const int* in_sizes, int n_in,
                              void* d_out, int out_size, void* d_ws, size_t ws_size,
                              hipStream_t stream)
{
    const float* x  = (const float*)d_in[0];
    const float* Wq = (const float*)d_in[1];
    const float* bq = (const float*)d_in[2];
    const float* Wk = (const float*)d_in[3];
    const float* bk = (const float*)d_in[4];
    const float* Wv = (const float*)d_in[5];
    const float* bv = (const float*)d_in[6];
    const float* Wo = (const float*)d_in[7];
    const float* bo = (const float*)d_in[8];
    const float* W1 = (const float*)d_in[9];
    const float* b1 = (const float*)d_in[10];
    const float* W2 = (const float*)d_in[11];
    const float* b2 = (const float*)d_in[12];
    const float* hs = (const float*)d_in[13];

    const size_t WELEM = (size_t)En * En;      // 1M elems per weight matrix
    unsigned short* W1b = (unsigned short*)d_ws;
    unsigned short* Wqb = W1b + WELEM;
    unsigned short* Wkb = Wqb + WELEM;
    unsigned short* Wvb = Wkb + WELEM;
    unsigned short* t1b = Wvb + WELEM;         // 4096*1024 bf16
    unsigned short* qb  = t1b + (size_t)Mn * En;
    unsigned short* kb  = qb  + (size_t)Mn * En;
    unsigned short* vb  = kb  + (size_t)Mn * En;
    float* t2   = (float*)(vb + (size_t)Mn * En);   // 4096*64 fp32
    float* gate = t2 + (size_t)Mn * SIGn;           // 4096*16 fp32
    unsigned short* Wob = W1b;   // alias: W1b dead after t1 GEMM
    unsigned short* ob  = t1b;   // alias: t1b dead after gemm_t2

    dim3 blk(256);
    const int castGrid = (int)(WELEM / 8 / 256);   // 512 blocks

    // Weight casts (W1/Wq/Wk/Wv).
    cast_bf16<<<castGrid, blk, 0, stream>>>(W1, W1b, (int)(WELEM / 8));
    cast_bf16<<<castGrid, blk, 0, stream>>>(Wq, Wqb, (int)(WELEM / 8));
    cast_bf16<<<castGrid, blk, 0, stream>>>(Wk, Wkb, (int)(WELEM / 8));
    cast_bf16<<<castGrid, blk, 0, stream>>>(Wv, Wvb, (int)(WELEM / 8));

    dim3 gemmGrid(En / 128, Mn / 128);   // (8, 32)

    // Gate path.
    mfma_gemm<0, 1, 1><<<gemmGrid, blk, 0, stream>>>(
        x, W1b, b1, t1b, Mn, HIDn, En, 1.0f);
    gemm_t2<<<dim3(Mn / 64), blk, 0, stream>>>(t1b, W2, b2, t2);
    gate_kernel<<<dim3(Mn / 256), blk, 0, stream>>>(t2, hs, gate);

    // Projections (q scaled by d^-0.5 = 0.125).
    mfma_gemm<0, 0, 1><<<gemmGrid, blk, 0, stream>>>(
        x, Wqb, bq, qb, Mn, En, En, 0.125f);
    mfma_gemm<0, 0, 1><<<gemmGrid, blk, 0, stream>>>(
        x, Wkb, bk, kb, Mn, En, En, 1.0f);
    mfma_gemm<0, 0, 1><<<gemmGrid, blk, 0, stream>>>(
        x, Wvb, bv, vb, Mn, En, En, 1.0f);

    // Wo cast into W1b's slot (W1b no longer needed).
    cast_bf16<<<castGrid, blk, 0, stream>>>(Wo, Wob, (int)(WELEM / 8));

    // Attention with gate folded in; ob reuses t1b's slot.
    attn_kernel<<<dim3(Bn * Hn, Tn / 64), blk, 0, stream>>>(qb, kb, vb, gate, ob);

    // Output projection (bf16 A) straight into d_out (fp32).
    mfma_gemm<1, 0, 0><<<gemmGrid, blk, 0, stream>>>(
        ob, Wob, bo, (float*)d_out, Mn, En, En, 1.0f);
}

// Round 3
// 361.642 us; speedup vs baseline: 1.8498x; 1.8498x over previous
//
#include <hip/hip_runtime.h>

// Problem constants
#define Tn   1024
#define Bn   4
#define En   1024
#define Hn   16
#define HIDn 1024
#define SIGn 64
#define Mn   (Tn * Bn)   // 4096 rows when x viewed as (T*B, E)

typedef short  s8x8  __attribute__((ext_vector_type(8)));   // 8 bf16 (4 VGPRs)
typedef float  f32x4 __attribute__((ext_vector_type(4)));   // MFMA acc

__device__ __forceinline__ float bf2f(unsigned short u) {
    return __uint_as_float(((unsigned int)u) << 16);
}
__device__ __forceinline__ unsigned short f2bf(float f) {
    unsigned int x = __float_as_uint(f);
    unsigned int r = (x + 0x7fffu + ((x >> 16) & 1u)) >> 16;   // RNE
    return (unsigned short)r;
}

// global -> LDS direct copy, 16B per lane. LDS dest must be wave-uniform;
// HW writes lds_base + lane*16 (guide §5). Global src is per-lane.
__device__ __forceinline__ void gload_lds16(const void* g, void* l) {
    __builtin_amdgcn_global_load_lds(
        (const __attribute__((address_space(1))) unsigned int*)g,
        (__attribute__((address_space(3))) unsigned int*)l, 16, 0, 0);
}

// ---------------------------------------------------------------------------
// fp32 -> bf16 cast, 8 elems/thread
// ---------------------------------------------------------------------------
__global__ __launch_bounds__(256) void cast_bf16(
    const float* __restrict__ s, unsigned short* __restrict__ d, int n8)
{
    int i = blockIdx.x * 256 + threadIdx.x;
    if (i >= n8) return;
    const float4* p = (const float4*)(s + (size_t)i * 8);
    float4 a = p[0], b = p[1];
    s8x8 o;
    o[0] = (short)f2bf(a.x); o[1] = (short)f2bf(a.y);
    o[2] = (short)f2bf(a.z); o[3] = (short)f2bf(a.w);
    o[4] = (short)f2bf(b.x); o[5] = (short)f2bf(b.y);
    o[6] = (short)f2bf(b.z); o[7] = (short)f2bf(b.w);
    *(s8x8*)(d + (size_t)i * 8) = o;
}

// ---------------------------------------------------------------------------
// bf16 MFMA GEMM (unchanged from round 2 — passing).
// C[m][n] = act((sum_k A[m][k]*W[n][k] + bias[n]) * scale)
// ---------------------------------------------------------------------------
template <int A_BF16, int RELU, int OUT_BF16>
__global__ __launch_bounds__(256) void mfma_gemm(
    const void* __restrict__ Ap, const unsigned short* __restrict__ Wb,
    const float* __restrict__ bias, void* __restrict__ Cp,
    int M, int N, int K, float scale)
{
    __shared__ short As[128 * 40];
    __shared__ short Bs[128 * 40];
    const int tid  = threadIdx.x;
    const int wave = tid >> 6;
    const int lane = tid & 63;
    const int ln15 = lane & 15;
    const int kq   = lane >> 4;
    const int wr   = wave >> 1;
    const int wc   = wave & 1;
    const size_t rowA0 = (size_t)blockIdx.y * 128;
    const size_t rowB0 = (size_t)blockIdx.x * 128;

    const int srow = tid >> 1;
    const int scol = (tid & 1) * 16;

    f32x4 acc[4][4];
#pragma unroll
    for (int m = 0; m < 4; m++)
#pragma unroll
        for (int n = 0; n < 4; n++) acc[m][n] = (f32x4){0.f, 0.f, 0.f, 0.f};

    const float*          Af = (const float*)Ap;
    const unsigned short* Ab = (const unsigned short*)Ap;

    for (int k0 = 0; k0 < K; k0 += 32) {
        s8x8 v0, v1;
        if (A_BF16) {
            const s8x8* src = (const s8x8*)(Ab + (rowA0 + srow) * K + k0 + scol);
            v0 = src[0]; v1 = src[1];
        } else {
            const float4* src = (const float4*)(Af + (rowA0 + srow) * K + k0 + scol);
            float4 a = src[0], b = src[1], c = src[2], d = src[3];
            v0[0] = (short)f2bf(a.x); v0[1] = (short)f2bf(a.y);
            v0[2] = (short)f2bf(a.z); v0[3] = (short)f2bf(a.w);
            v0[4] = (short)f2bf(b.x); v0[5] = (short)f2bf(b.y);
            v0[6] = (short)f2bf(b.z); v0[7] = (short)f2bf(b.w);
            v1[0] = (short)f2bf(c.x); v1[1] = (short)f2bf(c.y);
            v1[2] = (short)f2bf(c.z); v1[3] = (short)f2bf(c.w);
            v1[4] = (short)f2bf(d.x); v1[5] = (short)f2bf(d.y);
            v1[6] = (short)f2bf(d.z); v1[7] = (short)f2bf(d.w);
        }
        *(s8x8*)&As[srow * 40 + scol]     = v0;
        *(s8x8*)&As[srow * 40 + scol + 8] = v1;
        {
            const s8x8* src = (const s8x8*)(Wb + (rowB0 + srow) * K + k0 + scol);
            *(s8x8*)&Bs[srow * 40 + scol]     = src[0];
            *(s8x8*)&Bs[srow * 40 + scol + 8] = src[1];
        }
        __syncthreads();

        s8x8 af[4], bf[4];
#pragma unroll
        for (int m = 0; m < 4; m++)
            af[m] = *(const s8x8*)&As[(wr * 64 + m * 16 + ln15) * 40 + kq * 8];
#pragma unroll
        for (int n = 0; n < 4; n++)
            bf[n] = *(const s8x8*)&Bs[(wc * 64 + n * 16 + ln15) * 40 + kq * 8];
#pragma unroll
        for (int m = 0; m < 4; m++)
#pragma unroll
            for (int n = 0; n < 4; n++)
                acc[m][n] = __builtin_amdgcn_mfma_f32_16x16x32_bf16(
                    af[m], bf[n], acc[m][n], 0, 0, 0);
        __syncthreads();
    }

    float bcol[4];
#pragma unroll
    for (int n = 0; n < 4; n++)
        bcol[n] = bias[rowB0 + wc * 64 + n * 16 + ln15];
#pragma unroll
    for (int m = 0; m < 4; m++) {
        size_t gr0 = rowA0 + wr * 64 + m * 16 + kq * 4;
#pragma unroll
        for (int n = 0; n < 4; n++) {
            size_t gc = rowB0 + wc * 64 + n * 16 + ln15;
#pragma unroll
            for (int j = 0; j < 4; j++) {
                float vv = (acc[m][n][j] + bcol[n]) * scale;
                if (RELU) vv = fmaxf(vv, 0.f);
                if (OUT_BF16)
                    ((unsigned short*)Cp)[(gr0 + j) * N + gc] = f2bf(vv);
                else
                    ((float*)Cp)[(gr0 + j) * N + gc] = vv;
            }
        }
    }
}

// ---------------------------------------------------------------------------
// t2 = t1(bf16) @ W2^T + b2  (unchanged)
// ---------------------------------------------------------------------------
__global__ __launch_bounds__(256) void gemm_t2(
    const unsigned short* __restrict__ A, const float* __restrict__ W,
    const float* __restrict__ b2, float* __restrict__ C)
{
    __shared__ float As[64][33];
    __shared__ float Ws[64][33];
    const int tid = threadIdx.x;
    const int tx = tid & 15;
    const int tg = tid >> 4;
    const int bm = blockIdx.x;
    const unsigned short* Ab = A + (size_t)bm * 64 * HIDn;

    float acc[4][4] = {{0.f}};

    for (int k0 = 0; k0 < HIDn; k0 += 32) {
        {
            int row = tid >> 2;
            int col = (tid & 3) * 8;
            s8x8 s = *(const s8x8*)(Ab + (size_t)row * HIDn + k0 + col);
#pragma unroll
            for (int i = 0; i < 8; i++)
                As[row][col + i] = bf2f((unsigned short)s[i]);
        }
#pragma unroll
        for (int i = 0; i < 2; i++) {
            int idx = tid + i * 256;
            int row = idx >> 3;
            int col = (idx & 7) * 4;
            float4 vw = *(const float4*)(W + (size_t)row * HIDn + k0 + col);
            Ws[row][col + 0] = vw.x; Ws[row][col + 1] = vw.y;
            Ws[row][col + 2] = vw.z; Ws[row][col + 3] = vw.w;
        }
        __syncthreads();
#pragma unroll 8
        for (int kk = 0; kk < 32; kk++) {
            float a[4], w[4];
#pragma unroll
            for (int i = 0; i < 4; i++) a[i] = As[tg * 4 + i][kk];
#pragma unroll
            for (int j = 0; j < 4; j++) w[j] = Ws[tx * 4 + j][kk];
#pragma unroll
            for (int i = 0; i < 4; i++)
#pragma unroll
                for (int j = 0; j < 4; j++)
                    acc[i][j] += a[i] * w[j];
        }
        __syncthreads();
    }
#pragma unroll
    for (int i = 0; i < 4; i++)
#pragma unroll
        for (int j = 0; j < 4; j++)
            C[(size_t)(bm * 64 + tg * 4 + i) * SIGn + tx * 4 + j] =
                acc[i][j] + b2[tx * 4 + j];
}

// ---------------------------------------------------------------------------
// Gate (unchanged)
// ---------------------------------------------------------------------------
__global__ __launch_bounds__(256) void gate_kernel(
    const float* __restrict__ t2, const float* __restrict__ hs,
    float* __restrict__ gate)
{
    __shared__ float hss[Hn][SIGn];
    const int tid = threadIdx.x;
#pragma unroll
    for (int i = 0; i < 4; i++) {
        int idx = tid + i * 256;
        hss[idx >> 6][idx & 63] = hs[idx];
    }
    __syncthreads();

    const int m = blockIdx.x * 256 + tid;
    const float* row = t2 + (size_t)m * SIGn;
    float logits[Hn];
    float mx = -1e30f;
#pragma unroll
    for (int h = 0; h < Hn; h++) {
        float s = 0.f;
#pragma unroll 8
        for (int s0 = 0; s0 < SIGn; s0++) s += row[s0] * hss[h][s0];
        logits[h] = s;
        mx = fmaxf(mx, s);
    }
    float sum = 0.f;
#pragma unroll
    for (int h = 0; h < Hn; h++) {
        logits[h] = __expf(logits[h] - mx);
        sum += logits[h];
    }
    float inv = 1.f / sum;
#pragma unroll
    for (int h = 0; h < Hn; h++) gate[(size_t)m * Hn + h] = logits[h] * inv;
}

// ---------------------------------------------------------------------------
// V transpose: vb (m=t*Bn+b, e=h*64+d) -> vt[(b*16+h)*64 + d][t]  (bf16).
// LDS-tiled so both sides stay coalesced. ~16 MB traffic.
// ---------------------------------------------------------------------------
__global__ __launch_bounds__(256) void transpose_v(
    const unsigned short* __restrict__ vb, unsigned short* __restrict__ vt)
{
    __shared__ unsigned short ts[64][65];
    const int bh = blockIdx.x;
    const int b = bh >> 4, h = bh & 15;
    const int t0 = blockIdx.y * 64;
    const int tid = threadIdx.x;
    {
        int tr = tid >> 2, dq = (tid & 3) * 16;
        const unsigned short* src =
            vb + ((size_t)(t0 + tr) * Bn + b) * En + h * 64 + dq;
        s8x8 a = *(const s8x8*)src;
        s8x8 c = *(const s8x8*)(src + 8);
#pragma unroll
        for (int i = 0; i < 8; i++) {
            ts[tr][dq + i]     = (unsigned short)a[i];
            ts[tr][dq + 8 + i] = (unsigned short)c[i];
        }
    }
    __syncthreads();
    {
        int dr = tid >> 2, tq = (tid & 3) * 16;
        unsigned short* dst = vt + ((size_t)bh * 64 + dr) * Tn + t0 + tq;
        s8x8 o0, o1;
#pragma unroll
        for (int i = 0; i < 8; i++) {
            o0[i] = (short)ts[tq + i][dr];
            o1[i] = (short)ts[tq + 8 + i][dr];
        }
        *(s8x8*)dst = o0;
        *(s8x8*)(dst + 8) = o1;
    }
}

// ---------------------------------------------------------------------------
// MFMA flash attention. Block = (b,h) x 64-row Q tile, 4 waves, each wave
// owns a 16-row strip. K and V^T tiles (64 x 64 bf16, 128B rows) staged via
// global_load_lds (linear LDS dest; XOR swizzle chunk^=(row&7) folded into
// the per-lane GLOBAL source address, m173 pattern) -> ds_read_b128 frag
// reads are <=2-way conflicts. Double-buffered, 2-phase schedule.
// Online softmax wave-parallel; P routed through per-wave-private LDS strip
// (wave-lockstep, no barrier). Gate folded into epilogue.
// LDS 40KB -> 4 blocks/CU. grid (64,16) = 1024 blocks = full residency.
// ---------------------------------------------------------------------------
__global__ __launch_bounds__(256, 4) void attn_mfma(
    const unsigned short* __restrict__ q, const unsigned short* __restrict__ k,
    const unsigned short* __restrict__ vt, const float* __restrict__ gate,
    unsigned short* __restrict__ o)
{
    __shared__ __align__(16) short Kls[2][64 * 64];
    __shared__ __align__(16) short Vls[2][64 * 64];
    __shared__ __align__(16) short Pls[4][16 * 64];

    const int tid  = threadIdx.x;
    const int w    = tid >> 6;
    const int lane = tid & 63;
    const int ln   = lane & 15;
    const int kq   = lane >> 4;
    const int bh   = blockIdx.x;
    const int b    = bh >> 4;
    const int h    = bh & 15;
    const int qt   = blockIdx.y;

    // Q fragments, in registers for the whole kernel.
    // A-frag layout: lane holds Q[row=ln][k = kk*32 + kq*8 + j].
    s8x8 qf[2];
    {
        const int qrow = qt * 64 + w * 16 + ln;
        const unsigned short* src =
            q + ((size_t)qrow * Bn + b) * En + h * 64 + kq * 8;
        qf[0] = *(const s8x8*)(src);
        qf[1] = *(const s8x8*)(src + 32);
    }

    f32x4 O[4];
    float mrun[4], lrun[4];
#pragma unroll
    for (int n = 0; n < 4; n++) O[n] = (f32x4){0.f, 0.f, 0.f, 0.f};
#pragma unroll
    for (int j = 0; j < 4; j++) { mrun[j] = -1e30f; lrun[j] = 0.f; }

    const int srow0 = w * 16 + (lane >> 3);   // staging row for i=0

    auto stage = [&](int bufi, int s0) {
#pragma unroll
        for (int i = 0; i < 2; i++) {
            int row = srow0 + i * 8;
            int c   = (lane & 7) ^ (row & 7);          // pre-swizzled source chunk
            const unsigned short* gk =
                k + ((size_t)(s0 + row) * Bn + b) * En + h * 64 + c * 8;
            gload_lds16(gk, &Kls[bufi][w * 1024 + i * 512]);
            const unsigned short* gv =
                vt + ((size_t)bh * 64 + row) * Tn + s0 + c * 8;
            gload_lds16(gv, &Vls[bufi][w * 1024 + i * 512]);
        }
    };

    stage(0, 0);
    asm volatile("s_waitcnt vmcnt(0)" ::: "memory");
    __syncthreads();

    int cur = 0;
    for (int t = 0; t < Tn / 64; t++) {
        if (t + 1 < Tn / 64) stage(cur ^ 1, (t + 1) * 64);   // prefetch next tile

        // ---- S = Q K^T (wave strip 16 x 64) ----
        f32x4 S[4];
#pragma unroll
        for (int n = 0; n < 4; n++) {
            S[n] = (f32x4){0.f, 0.f, 0.f, 0.f};
#pragma unroll
            for (int kk = 0; kk < 2; kk++) {
                int row = n * 16 + ln;
                int cc  = (kk * 4 + kq) ^ (row & 7);
                s8x8 kf = *(const s8x8*)&Kls[cur][row * 64 + cc * 8];
                S[n] = __builtin_amdgcn_mfma_f32_16x16x32_bf16(qf[kk], kf, S[n], 0, 0, 0);
            }
        }

        // ---- online softmax; C/D layout row = kq*4+jj, col = n*16+ln ----
#pragma unroll
        for (int jj = 0; jj < 4; jj++) {
            float rm = fmaxf(fmaxf(S[0][jj], S[1][jj]), fmaxf(S[2][jj], S[3][jj]));
            rm = fmaxf(rm, __shfl_xor(rm, 1));
            rm = fmaxf(rm, __shfl_xor(rm, 2));
            rm = fmaxf(rm, __shfl_xor(rm, 4));
            rm = fmaxf(rm, __shfl_xor(rm, 8));
            float mnew = fmaxf(mrun[jj], rm);
            float fs = __expf(mrun[jj] - mnew);
            float ps = 0.f;
            const int prow = kq * 4 + jj;
#pragma unroll
            for (int n = 0; n < 4; n++) {
                float p = __expf(S[n][jj] - mnew);
                ps += p;
                int col = n * 16 + ln;
                Pls[w][prow * 64 + (((col >> 3) ^ (prow & 7)) << 3) + (col & 7)] =
                    (short)f2bf(p);
            }
            ps += __shfl_xor(ps, 1);
            ps += __shfl_xor(ps, 2);
            ps += __shfl_xor(ps, 4);
            ps += __shfl_xor(ps, 8);
            lrun[jj] = lrun[jj] * fs + ps;
            mrun[jj] = mnew;
#pragma unroll
            for (int n = 0; n < 4; n++) O[n][jj] *= fs;
        }

        // ---- O += P V  (A-frag from Pls, B-frag from Vls = V^T) ----
#pragma unroll
        for (int kk = 0; kk < 2; kk++) {
            int cp = (kk * 4 + kq) ^ (ln & 7);
            s8x8 pa = *(const s8x8*)&Pls[w][ln * 64 + cp * 8];
#pragma unroll
            for (int n = 0; n < 4; n++) {
                int row = n * 16 + ln;
                int cv  = (kk * 4 + kq) ^ (row & 7);
                s8x8 vf = *(const s8x8*)&Vls[cur][row * 64 + cv * 8];
                O[n] = __builtin_amdgcn_mfma_f32_16x16x32_bf16(pa, vf, O[n], 0, 0, 0);
            }
        }

        asm volatile("s_waitcnt vmcnt(0)" ::: "memory");
        __syncthreads();
        cur ^= 1;
    }

    // ---- epilogue: normalize, gate, bf16 write in (m, e) layout ----
#pragma unroll
    for (int jj = 0; jj < 4; jj++) {
        int tq = qt * 64 + w * 16 + kq * 4 + jj;
        size_t m = (size_t)tq * Bn + b;
        float g = gate[m * Hn + h] / lrun[jj];
#pragma unroll
        for (int n = 0; n < 4; n++)
            o[m * En + h * 64 + n * 16 + ln] = f2bf(O[n][jj] * g);
    }
}

// ---------------------------------------------------------------------------
// Workspace layout (41.25 MB, same as round 2):
//   W1b 2MB | Wqb 2MB | Wkb 2MB | Wvb 2MB | t1b 8MB | qb 8MB | kb 8MB |
//   vb 8MB | t2 1MB | gate 0.25MB
// Aliases (serialized by stream order):
//   vt  <- t1b slot (t1b dead after gemm_t2)
//   Wob <- W1b slot (W1b dead after t1 GEMM)
//   ob  <- vb slot  (vb dead after transpose_v)
// ---------------------------------------------------------------------------
extern "C" void kernel_launch(void* const* d_in, const int* in_sizes, int n_in,
                              void* d_out, int out_size, void* d_ws, size_t ws_size,
                              hipStream_t stream)
{
    const float* x  = (const float*)d_in[0];
    const float* Wq = (const float*)d_in[1];
    const float* bq = (const float*)d_in[2];
    const float* Wk = (const float*)d_in[3];
    const float* bk = (const float*)d_in[4];
    const float* Wv = (const float*)d_in[5];
    const float* bv = (const float*)d_in[6];
    const float* Wo = (const float*)d_in[7];
    const float* bo = (const float*)d_in[8];
    const float* W1 = (const float*)d_in[9];
    const float* b1 = (const float*)d_in[10];
    const float* W2 = (const float*)d_in[11];
    const float* b2 = (const float*)d_in[12];
    const float* hs = (const float*)d_in[13];

    const size_t WELEM = (size_t)En * En;
    unsigned short* W1b = (unsigned short*)d_ws;
    unsigned short* Wqb = W1b + WELEM;
    unsigned short* Wkb = Wqb + WELEM;
    unsigned short* Wvb = Wkb + WELEM;
    unsigned short* t1b = Wvb + WELEM;
    unsigned short* qb  = t1b + (size_t)Mn * En;
    unsigned short* kb  = qb  + (size_t)Mn * En;
    unsigned short* vb  = kb  + (size_t)Mn * En;
    float* t2   = (float*)(vb + (size_t)Mn * En);
    float* gate = t2 + (size_t)Mn * SIGn;
    unsigned short* Wob = W1b;   // alias
    unsigned short* vtb = t1b;   // alias
    unsigned short* ob  = vb;    // alias

    dim3 blk(256);
    const int castGrid = (int)(WELEM / 8 / 256);

    cast_bf16<<<castGrid, blk, 0, stream>>>(W1, W1b, (int)(WELEM / 8));
    cast_bf16<<<castGrid, blk, 0, stream>>>(Wq, Wqb, (int)(WELEM / 8));
    cast_bf16<<<castGrid, blk, 0, stream>>>(Wk, Wkb, (int)(WELEM / 8));
    cast_bf16<<<castGrid, blk, 0, stream>>>(Wv, Wvb, (int)(WELEM / 8));

    dim3 gemmGrid(En / 128, Mn / 128);

    // Gate path (t1b dead after gemm_t2 -> slot becomes vt).
    mfma_gemm<0, 1, 1><<<gemmGrid, blk, 0, stream>>>(
        x, W1b, b1, t1b, Mn, HIDn, En, 1.0f);
    gemm_t2<<<dim3(Mn / 64), blk, 0, stream>>>(t1b, W2, b2, t2);
    gate_kernel<<<dim3(Mn / 256), blk, 0, stream>>>(t2, hs, gate);

    // Projections (q scaled by d^-0.5 = 0.125).
    mfma_gemm<0, 0, 1><<<gemmGrid, blk, 0, stream>>>(
        x, Wqb, bq, qb, Mn, En, En, 0.125f);
    mfma_gemm<0, 0, 1><<<gemmGrid, blk, 0, stream>>>(
        x, Wkb, bk, kb, Mn, En, En, 1.0f);
    mfma_gemm<0, 0, 1><<<gemmGrid, blk, 0, stream>>>(
        x, Wvb, bv, vb, Mn, En, En, 1.0f);

    // V -> V^T per (b,h) for the attention PV B-operand.
    transpose_v<<<dim3(Bn * Hn, Tn / 64), blk, 0, stream>>>(vb, vtb);

    // Wo cast into the dead W1b slot.
    cast_bf16<<<castGrid, blk, 0, stream>>>(Wo, Wob, (int)(WELEM / 8));

    // MFMA flash attention, gate folded in; ob reuses vb's slot.
    attn_mfma<<<dim3(Bn * Hn, Tn / 64), blk, 0, stream>>>(qb, kb, vtb, gate, ob);

    // Output projection (bf16 A) straight into d_out (fp32).
    mfma_gemm<1, 0, 0><<<gemmGrid, blk, 0, stream>>>(
        ob, Wob, bo, (float*)d_out, Mn, En, En, 1.0f);
}

// Round 4
// 201.862 us; speedup vs baseline: 3.3139x; 1.7915x over previous
//
#include <hip/hip_runtime.h>

// Problem constants
#define Tn   1024
#define Bn   4
#define En   1024
#define Hn   16
#define HIDn 1024
#define SIGn 64
#define Mn   (Tn * Bn)   // 4096 rows when x viewed as (T*B, E)

typedef short  s8x8  __attribute__((ext_vector_type(8)));   // 8 bf16 (4 VGPRs)
typedef float  f32x4 __attribute__((ext_vector_type(4)));   // MFMA acc

__device__ __forceinline__ float bf2f(unsigned short u) {
    return __uint_as_float(((unsigned int)u) << 16);
}
__device__ __forceinline__ unsigned short f2bf(float f) {
    unsigned int x = __float_as_uint(f);
    unsigned int r = (x + 0x7fffu + ((x >> 16) & 1u)) >> 16;   // RNE
    return (unsigned short)r;
}

// global -> LDS direct copy, 16B/lane. LDS dest is wave-uniform base
// (HW writes base + lane*16); global src is per-lane (swizzle goes there).
__device__ __forceinline__ void gload_lds16(const void* g, void* l) {
    __builtin_amdgcn_global_load_lds(
        (const __attribute__((address_space(1))) unsigned int*)g,
        (__attribute__((address_space(3))) unsigned int*)l, 16, 0, 0);
}

// ---------------------------------------------------------------------------
// fp32 -> bf16 cast, 8 elems/thread
// ---------------------------------------------------------------------------
__global__ __launch_bounds__(256) void cast_bf16(
    const float* __restrict__ s, unsigned short* __restrict__ d, int n8)
{
    int i = blockIdx.x * 256 + threadIdx.x;
    if (i >= n8) return;
    const float4* p = (const float4*)(s + (size_t)i * 8);
    float4 a = p[0], b = p[1];
    s8x8 o;
    o[0] = (short)f2bf(a.x); o[1] = (short)f2bf(a.y);
    o[2] = (short)f2bf(a.z); o[3] = (short)f2bf(a.w);
    o[4] = (short)f2bf(b.x); o[5] = (short)f2bf(b.y);
    o[6] = (short)f2bf(b.z); o[7] = (short)f2bf(b.w);
    *(s8x8*)(d + (size_t)i * 8) = o;
}

// ---------------------------------------------------------------------------
// Fused projection GEMM: [t1|q|k|v] = act((x @ Wcat^T + bcat) * scale).
// M=4096, N=4096 (4 x 1024 ranges), K=1024. Tile 128x128, BK=32, 4 waves 2x2.
// Grid (32,32) = 1024 blocks = 4/CU. B staged via global_load_lds (linear LDS
// dest, XOR swizzle chunk^=(row>>1)&3 folded into the GLOBAL source addr);
// A staged fp32->bf16 inline with the same swizzle on the ds_write side.
// Frag ds_read_b128: 16 lanes spread over 8 bank-quads -> 2-way = free.
// Per-range epilogue (dst buffer / scale / relu) is block-uniform (bn>>3).
// ---------------------------------------------------------------------------
__global__ __launch_bounds__(256) void fused_proj(
    const float* __restrict__ X, const unsigned short* __restrict__ Wcat,
    const float* __restrict__ bcat,
    unsigned short* __restrict__ t1b, unsigned short* __restrict__ qb,
    unsigned short* __restrict__ kb, unsigned short* __restrict__ vb)
{
    __shared__ __align__(16) short As[128 * 32];
    __shared__ __align__(16) short Bs[128 * 32];
    const int tid  = threadIdx.x;
    const int wave = tid >> 6;
    const int lane = tid & 63;
    const int ln15 = lane & 15;
    const int kq   = lane >> 4;
    const int wr   = wave >> 1;
    const int wc   = wave & 1;
    const int bn   = blockIdx.x;            // 0..31 over N=4096
    const int bm   = blockIdx.y;            // 0..31 over M=4096
    const size_t rowA0 = (size_t)bm * 128;
    const size_t rowB0 = (size_t)bn * 128;

    const int brow0  = wave * 32 + (lane >> 2);   // B stage row (issue 0)
    const int bchunk = lane & 3;
    const int srow   = tid >> 1;                  // A stage row 0..127
    const int scol   = (tid & 1) * 16;            // A stage col 0/16

    f32x4 acc[4][4];
#pragma unroll
    for (int m = 0; m < 4; m++)
#pragma unroll
        for (int n = 0; n < 4; n++) acc[m][n] = (f32x4){0.f, 0.f, 0.f, 0.f};

    for (int k0 = 0; k0 < 1024; k0 += 32) {
        // ---- B tile via global_load_lds, pre-swizzled source ----
#pragma unroll
        for (int i = 0; i < 2; i++) {
            int row = brow0 + i * 16;
            int c   = bchunk ^ ((row >> 1) & 3);
            gload_lds16(Wcat + (rowB0 + row) * 1024 + k0 + c * 8,
                        &Bs[(wave * 32 + i * 16) * 32]);
        }
        // ---- A tile: fp32 load + cvt + swizzled ds_write ----
        {
            const float4* src = (const float4*)(X + (rowA0 + srow) * 1024 + k0 + scol);
            float4 a = src[0], b = src[1], c4 = src[2], d4 = src[3];
            s8x8 v0, v1;
            v0[0] = (short)f2bf(a.x);  v0[1] = (short)f2bf(a.y);
            v0[2] = (short)f2bf(a.z);  v0[3] = (short)f2bf(a.w);
            v0[4] = (short)f2bf(b.x);  v0[5] = (short)f2bf(b.y);
            v0[6] = (short)f2bf(b.z);  v0[7] = (short)f2bf(b.w);
            v1[0] = (short)f2bf(c4.x); v1[1] = (short)f2bf(c4.y);
            v1[2] = (short)f2bf(c4.z); v1[3] = (short)f2bf(c4.w);
            v1[4] = (short)f2bf(d4.x); v1[5] = (short)f2bf(d4.y);
            v1[6] = (short)f2bf(d4.z); v1[7] = (short)f2bf(d4.w);
            int sw = (srow >> 1) & 3;
            int c0 = (scol >> 3) ^ sw;
            int c1 = ((scol >> 3) + 1) ^ sw;
            *(s8x8*)&As[srow * 32 + c0 * 8] = v0;
            *(s8x8*)&As[srow * 32 + c1 * 8] = v1;
        }
        asm volatile("s_waitcnt vmcnt(0)" ::: "memory");
        __syncthreads();

        s8x8 af[4], bf[4];
#pragma unroll
        for (int m = 0; m < 4; m++) {
            int row = wr * 64 + m * 16 + ln15;
            af[m] = *(const s8x8*)&As[row * 32 + (kq ^ ((row >> 1) & 3)) * 8];
        }
#pragma unroll
        for (int n = 0; n < 4; n++) {
            int row = wc * 64 + n * 16 + ln15;
            bf[n] = *(const s8x8*)&Bs[row * 32 + (kq ^ ((row >> 1) & 3)) * 8];
        }
#pragma unroll
        for (int m = 0; m < 4; m++)
#pragma unroll
            for (int n = 0; n < 4; n++)
                acc[m][n] = __builtin_amdgcn_mfma_f32_16x16x32_bf16(
                    af[m], bf[n], acc[m][n], 0, 0, 0);
        __syncthreads();
    }

    // ---- epilogue: per-range dst/scale/relu (block-uniform) ----
    const int which = bn >> 3;
    unsigned short* dst = (which == 0) ? t1b : (which == 1) ? qb
                        : (which == 2) ? kb : vb;
    const float scale = (which == 1) ? 0.125f : 1.0f;
    const int   relu  = (which == 0);
    const int   cbase = (bn & 7) * 128;

    float bcol[4];
#pragma unroll
    for (int n = 0; n < 4; n++)
        bcol[n] = bcat[bn * 128 + wc * 64 + n * 16 + ln15];
#pragma unroll
    for (int m = 0; m < 4; m++) {
        size_t gr0 = rowA0 + wr * 64 + m * 16 + kq * 4;
#pragma unroll
        for (int n = 0; n < 4; n++) {
            int gc = cbase + wc * 64 + n * 16 + ln15;
#pragma unroll
            for (int j = 0; j < 4; j++) {
                float vv = (acc[m][n][j] + bcol[n]) * scale;
                if (relu) vv = fmaxf(vv, 0.f);
                dst[(gr0 + j) * 1024 + gc] = f2bf(vv);
            }
        }
    }
}

// ---------------------------------------------------------------------------
// Output projection: d_out = ob @ Wo^T + bo. M=4096, N=1024, K=1024.
// Tile 64x128 -> grid (8,64) = 512 blocks = 2/CU. Both operands bf16 via
// global_load_lds with the same swizzle scheme. fp32 output.
// ---------------------------------------------------------------------------
__global__ __launch_bounds__(256) void out_proj(
    const unsigned short* __restrict__ A, const unsigned short* __restrict__ W,
    const float* __restrict__ bias, float* __restrict__ C)
{
    __shared__ __align__(16) short As[64 * 32];
    __shared__ __align__(16) short Bs[128 * 32];
    const int tid  = threadIdx.x;
    const int wave = tid >> 6;
    const int lane = tid & 63;
    const int ln15 = lane & 15;
    const int kq   = lane >> 4;
    const int wr   = wave >> 1;
    const int wc   = wave & 1;
    const size_t rowA0 = (size_t)blockIdx.y * 64;
    const size_t rowB0 = (size_t)blockIdx.x * 128;

    const int lrow   = lane >> 2;
    const int lchunk = lane & 3;

    f32x4 acc[2][4];
#pragma unroll
    for (int m = 0; m < 2; m++)
#pragma unroll
        for (int n = 0; n < 4; n++) acc[m][n] = (f32x4){0.f, 0.f, 0.f, 0.f};

    for (int k0 = 0; k0 < 1024; k0 += 32) {
        {   // A tile 64x32: 1 issue/wave
            int row = wave * 16 + lrow;
            int c   = lchunk ^ ((row >> 1) & 3);
            gload_lds16(A + (rowA0 + row) * 1024 + k0 + c * 8,
                        &As[(wave * 16) * 32]);
        }
#pragma unroll
        for (int i = 0; i < 2; i++) {   // B tile 128x32: 2 issues/wave
            int row = wave * 32 + i * 16 + lrow;
            int c   = lchunk ^ ((row >> 1) & 3);
            gload_lds16(W + (rowB0 + row) * 1024 + k0 + c * 8,
                        &Bs[(wave * 32 + i * 16) * 32]);
        }
        asm volatile("s_waitcnt vmcnt(0)" ::: "memory");
        __syncthreads();

        s8x8 af[2], bf[4];
#pragma unroll
        for (int m = 0; m < 2; m++) {
            int row = wr * 32 + m * 16 + ln15;
            af[m] = *(const s8x8*)&As[row * 32 + (kq ^ ((row >> 1) & 3)) * 8];
        }
#pragma unroll
        for (int n = 0; n < 4; n++) {
            int row = wc * 64 + n * 16 + ln15;
            bf[n] = *(const s8x8*)&Bs[row * 32 + (kq ^ ((row >> 1) & 3)) * 8];
        }
#pragma unroll
        for (int m = 0; m < 2; m++)
#pragma unroll
            for (int n = 0; n < 4; n++)
                acc[m][n] = __builtin_amdgcn_mfma_f32_16x16x32_bf16(
                    af[m], bf[n], acc[m][n], 0, 0, 0);
        __syncthreads();
    }

    float bcol[4];
#pragma unroll
    for (int n = 0; n < 4; n++)
        bcol[n] = bias[rowB0 + wc * 64 + n * 16 + ln15];
#pragma unroll
    for (int m = 0; m < 2; m++) {
        size_t gr0 = rowA0 + wr * 32 + m * 16 + kq * 4;
#pragma unroll
        for (int n = 0; n < 4; n++) {
            size_t gc = rowB0 + wc * 64 + n * 16 + ln15;
#pragma unroll
            for (int j = 0; j < 4; j++)
                C[(gr0 + j) * 1024 + gc] = acc[m][n][j] + bcol[n];
        }
    }
}

// ---------------------------------------------------------------------------
// Fused t2 + gate: per block, 16 rows. t2 = t1 @ W2b^T + b2 (MFMA, K=1024),
// logits = t2 @ hs^T, softmax over 16 heads -> gate. Grid 256 blocks.
// ---------------------------------------------------------------------------
__global__ __launch_bounds__(256) void t2gate(
    const unsigned short* __restrict__ t1, const unsigned short* __restrict__ W2b,
    const float* __restrict__ b2, const float* __restrict__ hs,
    float* __restrict__ gate)
{
    __shared__ __align__(16) short As[16 * 32];
    __shared__ __align__(16) short Bs[64 * 32];
    __shared__ float t2s[16][65];
    __shared__ float hss[16][65];
    const int tid  = threadIdx.x;
    const int wave = tid >> 6;
    const int lane = tid & 63;
    const int ln15 = lane & 15;
    const int kq   = lane >> 4;
    const int m0   = blockIdx.x * 16;

    {   // stage head signatures (16x64 fp32), once
        int r = tid >> 4, c = (tid & 15) * 4;
        float4 v = *(const float4*)(hs + r * 64 + c);
        hss[r][c] = v.x; hss[r][c + 1] = v.y; hss[r][c + 2] = v.z; hss[r][c + 3] = v.w;
    }

    f32x4 acc = (f32x4){0.f, 0.f, 0.f, 0.f};
    for (int k0 = 0; k0 < 1024; k0 += 32) {
        if (tid < 64) {                       // A tile 16x32
            int row = tid >> 2, ch = tid & 3;
            int cs = ch ^ ((row >> 1) & 3);
            s8x8 vA = *(const s8x8*)(t1 + (size_t)(m0 + row) * 1024 + k0 + ch * 8);
            *(s8x8*)&As[row * 32 + cs * 8] = vA;
        }
        {                                     // B tile 64x32
            int row = tid >> 2, ch = tid & 3;
            int cs = ch ^ ((row >> 1) & 3);
            s8x8 vB = *(const s8x8*)(W2b + (size_t)row * 1024 + k0 + ch * 8);
            *(s8x8*)&Bs[row * 32 + cs * 8] = vB;
        }
        __syncthreads();
        int arow = ln15;
        int brow = wave * 16 + ln15;
        s8x8 af = *(const s8x8*)&As[arow * 32 + (kq ^ ((arow >> 1) & 3)) * 8];
        s8x8 bf = *(const s8x8*)&Bs[brow * 32 + (kq ^ ((brow >> 1) & 3)) * 8];
        acc = __builtin_amdgcn_mfma_f32_16x16x32_bf16(af, bf, acc, 0, 0, 0);
        __syncthreads();
    }

    // t2 tile to LDS: row = kq*4+j, col = wave*16+ln15
#pragma unroll
    for (int j = 0; j < 4; j++)
        t2s[kq * 4 + j][wave * 16 + ln15] = acc[j] + b2[wave * 16 + ln15];
    __syncthreads();

    // logits + softmax: thread = (row r, head hd)
    int r = tid >> 4, hd = tid & 15;
    float s = 0.f;
#pragma unroll 16
    for (int d = 0; d < 64; d++) s += t2s[r][d] * hss[hd][d];
    float mx = s;
    mx = fmaxf(mx, __shfl_xor(mx, 1));
    mx = fmaxf(mx, __shfl_xor(mx, 2));
    mx = fmaxf(mx, __shfl_xor(mx, 4));
    mx = fmaxf(mx, __shfl_xor(mx, 8));
    float e = __expf(s - mx);
    float sum = e;
    sum += __shfl_xor(sum, 1);
    sum += __shfl_xor(sum, 2);
    sum += __shfl_xor(sum, 4);
    sum += __shfl_xor(sum, 8);
    gate[(size_t)(m0 + r) * Hn + hd] = e / sum;
}

// ---------------------------------------------------------------------------
// V transpose: vb (m=t*Bn+b, e=h*64+d) -> vt[(b*16+h)*64 + d][t]  (bf16).
// ---------------------------------------------------------------------------
__global__ __launch_bounds__(256) void transpose_v(
    const unsigned short* __restrict__ vb, unsigned short* __restrict__ vt)
{
    __shared__ unsigned short ts[64][65];
    const int bh = blockIdx.x;
    const int b = bh >> 4, h = bh & 15;
    const int t0 = blockIdx.y * 64;
    const int tid = threadIdx.x;
    {
        int tr = tid >> 2, dq = (tid & 3) * 16;
        const unsigned short* src =
            vb + ((size_t)(t0 + tr) * Bn + b) * En + h * 64 + dq;
        s8x8 a = *(const s8x8*)src;
        s8x8 c = *(const s8x8*)(src + 8);
#pragma unroll
        for (int i = 0; i < 8; i++) {
            ts[tr][dq + i]     = (unsigned short)a[i];
            ts[tr][dq + 8 + i] = (unsigned short)c[i];
        }
    }
    __syncthreads();
    {
        int dr = tid >> 2, tq = (tid & 3) * 16;
        unsigned short* dst = vt + ((size_t)bh * 64 + dr) * Tn + t0 + tq;
        s8x8 o0, o1;
#pragma unroll
        for (int i = 0; i < 8; i++) {
            o0[i] = (short)ts[tq + i][dr];
            o1[i] = (short)ts[tq + 8 + i][dr];
        }
        *(s8x8*)dst = o0;
        *(s8x8*)(dst + 8) = o1;
    }
}

// ---------------------------------------------------------------------------
// MFMA flash attention (unchanged from round 3 — passing).
// ---------------------------------------------------------------------------
__global__ __launch_bounds__(256, 4) void attn_mfma(
    const unsigned short* __restrict__ q, const unsigned short* __restrict__ k,
    const unsigned short* __restrict__ vt, const float* __restrict__ gate,
    unsigned short* __restrict__ o)
{
    __shared__ __align__(16) short Kls[2][64 * 64];
    __shared__ __align__(16) short Vls[2][64 * 64];
    __shared__ __align__(16) short Pls[4][16 * 64];

    const int tid  = threadIdx.x;
    const int w    = tid >> 6;
    const int lane = tid & 63;
    const int ln   = lane & 15;
    const int kq   = lane >> 4;
    const int bh   = blockIdx.x;
    const int b    = bh >> 4;
    const int h    = bh & 15;
    const int qt   = blockIdx.y;

    s8x8 qf[2];
    {
        const int qrow = qt * 64 + w * 16 + ln;
        const unsigned short* src =
            q + ((size_t)qrow * Bn + b) * En + h * 64 + kq * 8;
        qf[0] = *(const s8x8*)(src);
        qf[1] = *(const s8x8*)(src + 32);
    }

    f32x4 O[4];
    float mrun[4], lrun[4];
#pragma unroll
    for (int n = 0; n < 4; n++) O[n] = (f32x4){0.f, 0.f, 0.f, 0.f};
#pragma unroll
    for (int j = 0; j < 4; j++) { mrun[j] = -1e30f; lrun[j] = 0.f; }

    const int srow0 = w * 16 + (lane >> 3);

    auto stage = [&](int bufi, int s0) {
#pragma unroll
        for (int i = 0; i < 2; i++) {
            int row = srow0 + i * 8;
            int c   = (lane & 7) ^ (row & 7);
            const unsigned short* gk =
                k + ((size_t)(s0 + row) * Bn + b) * En + h * 64 + c * 8;
            gload_lds16(gk, &Kls[bufi][w * 1024 + i * 512]);
            const unsigned short* gv =
                vt + ((size_t)bh * 64 + row) * Tn + s0 + c * 8;
            gload_lds16(gv, &Vls[bufi][w * 1024 + i * 512]);
        }
    };

    stage(0, 0);
    asm volatile("s_waitcnt vmcnt(0)" ::: "memory");
    __syncthreads();

    int cur = 0;
    for (int t = 0; t < Tn / 64; t++) {
        if (t + 1 < Tn / 64) stage(cur ^ 1, (t + 1) * 64);

        f32x4 S[4];
#pragma unroll
        for (int n = 0; n < 4; n++) {
            S[n] = (f32x4){0.f, 0.f, 0.f, 0.f};
#pragma unroll
            for (int kk = 0; kk < 2; kk++) {
                int row = n * 16 + ln;
                int cc  = (kk * 4 + kq) ^ (row & 7);
                s8x8 kf = *(const s8x8*)&Kls[cur][row * 64 + cc * 8];
                S[n] = __builtin_amdgcn_mfma_f32_16x16x32_bf16(qf[kk], kf, S[n], 0, 0, 0);
            }
        }

#pragma unroll
        for (int jj = 0; jj < 4; jj++) {
            float rm = fmaxf(fmaxf(S[0][jj], S[1][jj]), fmaxf(S[2][jj], S[3][jj]));
            rm = fmaxf(rm, __shfl_xor(rm, 1));
            rm = fmaxf(rm, __shfl_xor(rm, 2));
            rm = fmaxf(rm, __shfl_xor(rm, 4));
            rm = fmaxf(rm, __shfl_xor(rm, 8));
            float mnew = fmaxf(mrun[jj], rm);
            float fs = __expf(mrun[jj] - mnew);
            float ps = 0.f;
            const int prow = kq * 4 + jj;
#pragma unroll
            for (int n = 0; n < 4; n++) {
                float p = __expf(S[n][jj] - mnew);
                ps += p;
                int col = n * 16 + ln;
                Pls[w][prow * 64 + (((col >> 3) ^ (prow & 7)) << 3) + (col & 7)] =
                    (short)f2bf(p);
            }
            ps += __shfl_xor(ps, 1);
            ps += __shfl_xor(ps, 2);
            ps += __shfl_xor(ps, 4);
            ps += __shfl_xor(ps, 8);
            lrun[jj] = lrun[jj] * fs + ps;
            mrun[jj] = mnew;
#pragma unroll
            for (int n = 0; n < 4; n++) O[n][jj] *= fs;
        }

#pragma unroll
        for (int kk = 0; kk < 2; kk++) {
            int cp = (kk * 4 + kq) ^ (ln & 7);
            s8x8 pa = *(const s8x8*)&Pls[w][ln * 64 + cp * 8];
#pragma unroll
            for (int n = 0; n < 4; n++) {
                int row = n * 16 + ln;
                int cv  = (kk * 4 + kq) ^ (row & 7);
                s8x8 vf = *(const s8x8*)&Vls[cur][row * 64 + cv * 8];
                O[n] = __builtin_amdgcn_mfma_f32_16x16x32_bf16(pa, vf, O[n], 0, 0, 0);
            }
        }

        asm volatile("s_waitcnt vmcnt(0)" ::: "memory");
        __syncthreads();
        cur ^= 1;
    }

#pragma unroll
    for (int jj = 0; jj < 4; jj++) {
        int tq = qt * 64 + w * 16 + kq * 4 + jj;
        size_t m = (size_t)tq * Bn + b;
        float g = gate[m * Hn + h] / lrun[jj];
#pragma unroll
        for (int n = 0; n < 4; n++)
            o[m * En + h * 64 + n * 16 + ln] = f2bf(O[n][jj] * g);
    }
}

// ---------------------------------------------------------------------------
// Workspace layout (40.4 MB):
//   Wcat 8MB [W1|Wq|Wk|Wv] | W2b 128KB | bcat 16KB | gate 256KB |
//   t1b 8MB | qb 8MB | kb 8MB | vb 8MB
// Aliases (serialized by stream order):
//   vtb <- t1b slot (dead after t2gate); Wob <- Wcat slot (dead after
//   fused_proj); ob <- vb slot (dead after transpose_v).
// ---------------------------------------------------------------------------
extern "C" void kernel_launch(void* const* d_in, const int* in_sizes, int n_in,
                              void* d_out, int out_size, void* d_ws, size_t ws_size,
                              hipStream_t stream)
{
    const float* x  = (const float*)d_in[0];
    const float* Wq = (const float*)d_in[1];
    const float* bq = (const float*)d_in[2];
    const float* Wk = (const float*)d_in[3];
    const float* bk = (const float*)d_in[4];
    const float* Wv = (const float*)d_in[5];
    const float* bv = (const float*)d_in[6];
    const float* Wo = (const float*)d_in[7];
    const float* bo = (const float*)d_in[8];
    const float* W1 = (const float*)d_in[9];
    const float* b1 = (const float*)d_in[10];
    const float* W2 = (const float*)d_in[11];
    const float* b2 = (const float*)d_in[12];
    const float* hs = (const float*)d_in[13];

    const size_t WELEM = (size_t)En * En;
    unsigned short* Wcat = (unsigned short*)d_ws;            // 4*WELEM
    unsigned short* W2b  = Wcat + 4 * WELEM;                 // 64*1024
    float* bcat = (float*)(W2b + (size_t)SIGn * HIDn);       // 4096 floats
    float* gate = bcat + 4096;                               // 4096*16 floats
    unsigned short* t1b = (unsigned short*)(gate + (size_t)Mn * Hn);
    unsigned short* qb  = t1b + (size_t)Mn * En;
    unsigned short* kb  = qb  + (size_t)Mn * En;
    unsigned short* vb  = kb  + (size_t)Mn * En;
    unsigned short* Wob = Wcat;   // alias: Wcat dead after fused_proj
    unsigned short* vtb = t1b;    // alias: t1b dead after t2gate
    unsigned short* ob  = vb;     // alias: vb dead after transpose_v

    dim3 blk(256);
    const int castGrid = (int)(WELEM / 8 / 256);

    // Weight casts into Wcat [W1|Wq|Wk|Wv] and W2b.
    cast_bf16<<<castGrid, blk, 0, stream>>>(W1, Wcat + 0 * WELEM, (int)(WELEM / 8));
    cast_bf16<<<castGrid, blk, 0, stream>>>(Wq, Wcat + 1 * WELEM, (int)(WELEM / 8));
    cast_bf16<<<castGrid, blk, 0, stream>>>(Wk, Wcat + 2 * WELEM, (int)(WELEM / 8));
    cast_bf16<<<castGrid, blk, 0, stream>>>(Wv, Wcat + 3 * WELEM, (int)(WELEM / 8));
    cast_bf16<<<32, blk, 0, stream>>>(W2, W2b, (int)((size_t)SIGn * HIDn / 8));

    // bcat = [b1|bq|bk|bv]
    hipMemcpyAsync(bcat + 0 * En, b1, En * sizeof(float), hipMemcpyDeviceToDevice, stream);
    hipMemcpyAsync(bcat + 1 * En, bq, En * sizeof(float), hipMemcpyDeviceToDevice, stream);
    hipMemcpyAsync(bcat + 2 * En, bk, En * sizeof(float), hipMemcpyDeviceToDevice, stream);
    hipMemcpyAsync(bcat + 3 * En, bv, En * sizeof(float), hipMemcpyDeviceToDevice, stream);

    // All four projections in one dispatch (1024 blocks).
    fused_proj<<<dim3(32, 32), blk, 0, stream>>>(x, Wcat, bcat, t1b, qb, kb, vb);

    // Gate path (fused t2 + logits + softmax).
    t2gate<<<dim3(Mn / 16), blk, 0, stream>>>(t1b, W2b, b2, hs, gate);

    // V -> V^T per (b,h); vtb takes the dead t1b slot.
    transpose_v<<<dim3(Bn * Hn, Tn / 64), blk, 0, stream>>>(vb, vtb);

    // Wo cast into the dead Wcat slot.
    cast_bf16<<<castGrid, blk, 0, stream>>>(Wo, Wob, (int)(WELEM / 8));

    // MFMA flash attention, gate folded in; ob reuses vb's slot.
    attn_mfma<<<dim3(Bn * Hn, Tn / 64), blk, 0, stream>>>(qb, kb, vtb, gate, ob);

    // Output projection (both operands via global_load_lds) into d_out.
    out_proj<<<dim3(En / 128, Mn / 64), blk, 0, stream>>>(ob, Wob, bo, (float*)d_out);
}

// Round 5
// 165.322 us; speedup vs baseline: 4.0464x; 1.2210x over previous
//
#include <hip/hip_runtime.h>

// Problem constants
#define Tn   1024
#define Bn   4
#define En   1024
#define Hn   16
#define HIDn 1024
#define SIGn 64
#define Mn   (Tn * Bn)   // 4096 rows when x viewed as (T*B, E)

typedef short  s8x8  __attribute__((ext_vector_type(8)));   // 8 bf16 (4 VGPRs)
typedef float  f32x4 __attribute__((ext_vector_type(4)));   // MFMA acc

__device__ __forceinline__ float bf2f(unsigned short u) {
    return __uint_as_float(((unsigned int)u) << 16);
}
__device__ __forceinline__ unsigned short f2bf(float f) {
    unsigned int x = __float_as_uint(f);
    unsigned int r = (x + 0x7fffu + ((x >> 16) & 1u)) >> 16;   // RNE
    return (unsigned short)r;
}

// global -> LDS direct copy, 16B/lane. LDS dest is wave-uniform base
// (HW writes base + lane*16); global src is per-lane (swizzle goes there).
__device__ __forceinline__ void gload_lds16(const void* g, void* l) {
    __builtin_amdgcn_global_load_lds(
        (const __attribute__((address_space(1))) unsigned int*)g,
        (__attribute__((address_space(3))) unsigned int*)l, 16, 0, 0);
}

// ---------------------------------------------------------------------------
// fp32 -> bf16 cast, 8 elems/thread
// ---------------------------------------------------------------------------
__global__ __launch_bounds__(256) void cast_bf16(
    const float* __restrict__ s, unsigned short* __restrict__ d, int n8)
{
    int i = blockIdx.x * 256 + threadIdx.x;
    if (i >= n8) return;
    const float4* p = (const float4*)(s + (size_t)i * 8);
    float4 a = p[0], b = p[1];
    s8x8 o;
    o[0] = (short)f2bf(a.x); o[1] = (short)f2bf(a.y);
    o[2] = (short)f2bf(a.z); o[3] = (short)f2bf(a.w);
    o[4] = (short)f2bf(b.x); o[5] = (short)f2bf(b.y);
    o[6] = (short)f2bf(b.z); o[7] = (short)f2bf(b.w);
    *(s8x8*)(d + (size_t)i * 8) = o;
}

// 4 weight matrices -> Wcat in one dispatch. grid (WELEM/8/256, 4).
__global__ __launch_bounds__(256) void cast_w4(
    const float* __restrict__ W1, const float* __restrict__ Wq,
    const float* __restrict__ Wk, const float* __restrict__ Wv,
    unsigned short* __restrict__ Wcat)
{
    const size_t WELEM = (size_t)En * En;
    int y = blockIdx.y;
    const float* src = (y == 0) ? W1 : (y == 1) ? Wq : (y == 2) ? Wk : Wv;
    unsigned short* dst = Wcat + (size_t)y * WELEM;
    int i = blockIdx.x * 256 + threadIdx.x;
    const float4* p = (const float4*)(src + (size_t)i * 8);
    float4 a = p[0], b = p[1];
    s8x8 o;
    o[0] = (short)f2bf(a.x); o[1] = (short)f2bf(a.y);
    o[2] = (short)f2bf(a.z); o[3] = (short)f2bf(a.w);
    o[4] = (short)f2bf(b.x); o[5] = (short)f2bf(b.y);
    o[6] = (short)f2bf(b.z); o[7] = (short)f2bf(b.w);
    *(s8x8*)(dst + (size_t)i * 8) = o;
}

// bcat = [b1|bq|bk|bv]  (4096 floats), one dispatch.
__global__ __launch_bounds__(256) void bias_concat(
    const float* __restrict__ b1, const float* __restrict__ bq,
    const float* __restrict__ bk, const float* __restrict__ bv,
    float* __restrict__ bcat)
{
    int i = blockIdx.x * 256 + threadIdx.x;   // 0..4095
    int w = i >> 10;
    const float* s = (w == 0) ? b1 : (w == 1) ? bq : (w == 2) ? bk : bv;
    bcat[i] = s[i & 1023];
}

// ---------------------------------------------------------------------------
// Fused projection GEMM: [t1|q|k|v] = act((x @ Wcat^T + bcat) * scale).
// M=4096, N=4096, K=1024. Tile 128x128, BK=32, 4 waves 2x2, grid (32,32).
// PRE=1: A read from pre-cast bf16 xb via global_load_lds (2 issues/wave,
//        same source-side XOR swizzle as B) — no VALU cast in the hot loop.
// PRE=0: round-4 fallback (fp32 load + inline cvt + swizzled ds_write),
//        used only if ws_size can't hold xb.
// ---------------------------------------------------------------------------
template <int PRE>
__global__ __launch_bounds__(256) void fused_proj(
    const float* __restrict__ X, const unsigned short* __restrict__ Xb,
    const unsigned short* __restrict__ Wcat, const float* __restrict__ bcat,
    unsigned short* __restrict__ t1b, unsigned short* __restrict__ qb,
    unsigned short* __restrict__ kb, unsigned short* __restrict__ vb)
{
    __shared__ __align__(16) short As[128 * 32];
    __shared__ __align__(16) short Bs[128 * 32];
    const int tid  = threadIdx.x;
    const int wave = tid >> 6;
    const int lane = tid & 63;
    const int ln15 = lane & 15;
    const int kq   = lane >> 4;
    const int wr   = wave >> 1;
    const int wc   = wave & 1;
    const int bn   = blockIdx.x;            // 0..31 over N=4096
    const int bm   = blockIdx.y;            // 0..31 over M=4096
    const size_t rowA0 = (size_t)bm * 128;
    const size_t rowB0 = (size_t)bn * 128;

    const int lrow   = lane >> 2;           // 0..15
    const int lchunk = lane & 3;

    f32x4 acc[4][4];
#pragma unroll
    for (int m = 0; m < 4; m++)
#pragma unroll
        for (int n = 0; n < 4; n++) acc[m][n] = (f32x4){0.f, 0.f, 0.f, 0.f};

    for (int k0 = 0; k0 < 1024; k0 += 32) {
        // ---- B tile (128x32) via global_load_lds, pre-swizzled source ----
#pragma unroll
        for (int i = 0; i < 2; i++) {
            int row = wave * 32 + i * 16 + lrow;
            int c   = lchunk ^ ((row >> 1) & 3);
            gload_lds16(Wcat + (rowB0 + row) * 1024 + k0 + c * 8,
                        &Bs[(wave * 32 + i * 16) * 32]);
        }
        // ---- A tile (128x32) ----
        if (PRE) {
#pragma unroll
            for (int i = 0; i < 2; i++) {
                int row = wave * 32 + i * 16 + lrow;
                int c   = lchunk ^ ((row >> 1) & 3);
                gload_lds16(Xb + (rowA0 + row) * 1024 + k0 + c * 8,
                            &As[(wave * 32 + i * 16) * 32]);
            }
        } else {
            const int srow = tid >> 1;
            const int scol = (tid & 1) * 16;
            const float4* src = (const float4*)(X + (rowA0 + srow) * 1024 + k0 + scol);
            float4 a = src[0], b = src[1], c4 = src[2], d4 = src[3];
            s8x8 v0, v1;
            v0[0] = (short)f2bf(a.x);  v0[1] = (short)f2bf(a.y);
            v0[2] = (short)f2bf(a.z);  v0[3] = (short)f2bf(a.w);
            v0[4] = (short)f2bf(b.x);  v0[5] = (short)f2bf(b.y);
            v0[6] = (short)f2bf(b.z);  v0[7] = (short)f2bf(b.w);
            v1[0] = (short)f2bf(c4.x); v1[1] = (short)f2bf(c4.y);
            v1[2] = (short)f2bf(c4.z); v1[3] = (short)f2bf(c4.w);
            v1[4] = (short)f2bf(d4.x); v1[5] = (short)f2bf(d4.y);
            v1[6] = (short)f2bf(d4.z); v1[7] = (short)f2bf(d4.w);
            int sw = (srow >> 1) & 3;
            int c0 = (scol >> 3) ^ sw;
            int c1 = ((scol >> 3) + 1) ^ sw;
            *(s8x8*)&As[srow * 32 + c0 * 8] = v0;
            *(s8x8*)&As[srow * 32 + c1 * 8] = v1;
        }
        asm volatile("s_waitcnt vmcnt(0)" ::: "memory");
        __syncthreads();

        s8x8 af[4], bf[4];
#pragma unroll
        for (int m = 0; m < 4; m++) {
            int row = wr * 64 + m * 16 + ln15;
            af[m] = *(const s8x8*)&As[row * 32 + (kq ^ ((row >> 1) & 3)) * 8];
        }
#pragma unroll
        for (int n = 0; n < 4; n++) {
            int row = wc * 64 + n * 16 + ln15;
            bf[n] = *(const s8x8*)&Bs[row * 32 + (kq ^ ((row >> 1) & 3)) * 8];
        }
#pragma unroll
        for (int m = 0; m < 4; m++)
#pragma unroll
            for (int n = 0; n < 4; n++)
                acc[m][n] = __builtin_amdgcn_mfma_f32_16x16x32_bf16(
                    af[m], bf[n], acc[m][n], 0, 0, 0);
        __syncthreads();
    }

    // ---- epilogue: per-range dst/scale/relu (block-uniform) ----
    const int which = bn >> 3;
    unsigned short* dst = (which == 0) ? t1b : (which == 1) ? qb
                        : (which == 2) ? kb : vb;
    const float scale = (which == 1) ? 0.125f : 1.0f;
    const int   relu  = (which == 0);
    const int   cbase = (bn & 7) * 128;

    float bcol[4];
#pragma unroll
    for (int n = 0; n < 4; n++)
        bcol[n] = bcat[bn * 128 + wc * 64 + n * 16 + ln15];
#pragma unroll
    for (int m = 0; m < 4; m++) {
        size_t gr0 = rowA0 + wr * 64 + m * 16 + kq * 4;
#pragma unroll
        for (int n = 0; n < 4; n++) {
            int gc = cbase + wc * 64 + n * 16 + ln15;
#pragma unroll
            for (int j = 0; j < 4; j++) {
                float vv = (acc[m][n][j] + bcol[n]) * scale;
                if (relu) vv = fmaxf(vv, 0.f);
                dst[(gr0 + j) * 1024 + gc] = f2bf(vv);
            }
        }
    }
}

// ---------------------------------------------------------------------------
// Output projection: d_out = ob @ Wo^T + bo. M=4096, N=1024, K=1024.
// Tile 64x128 -> grid (8,64) = 512 blocks. Both operands via global_load_lds.
// ---------------------------------------------------------------------------
__global__ __launch_bounds__(256) void out_proj(
    const unsigned short* __restrict__ A, const unsigned short* __restrict__ W,
    const float* __restrict__ bias, float* __restrict__ C)
{
    __shared__ __align__(16) short As[64 * 32];
    __shared__ __align__(16) short Bs[128 * 32];
    const int tid  = threadIdx.x;
    const int wave = tid >> 6;
    const int lane = tid & 63;
    const int ln15 = lane & 15;
    const int kq   = lane >> 4;
    const int wr   = wave >> 1;
    const int wc   = wave & 1;
    const size_t rowA0 = (size_t)blockIdx.y * 64;
    const size_t rowB0 = (size_t)blockIdx.x * 128;

    const int lrow   = lane >> 2;
    const int lchunk = lane & 3;

    f32x4 acc[2][4];
#pragma unroll
    for (int m = 0; m < 2; m++)
#pragma unroll
        for (int n = 0; n < 4; n++) acc[m][n] = (f32x4){0.f, 0.f, 0.f, 0.f};

    for (int k0 = 0; k0 < 1024; k0 += 32) {
        {   // A tile 64x32: 1 issue/wave
            int row = wave * 16 + lrow;
            int c   = lchunk ^ ((row >> 1) & 3);
            gload_lds16(A + (rowA0 + row) * 1024 + k0 + c * 8,
                        &As[(wave * 16) * 32]);
        }
#pragma unroll
        for (int i = 0; i < 2; i++) {   // B tile 128x32: 2 issues/wave
            int row = wave * 32 + i * 16 + lrow;
            int c   = lchunk ^ ((row >> 1) & 3);
            gload_lds16(W + (rowB0 + row) * 1024 + k0 + c * 8,
                        &Bs[(wave * 32 + i * 16) * 32]);
        }
        asm volatile("s_waitcnt vmcnt(0)" ::: "memory");
        __syncthreads();

        s8x8 af[2], bf[4];
#pragma unroll
        for (int m = 0; m < 2; m++) {
            int row = wr * 32 + m * 16 + ln15;
            af[m] = *(const s8x8*)&As[row * 32 + (kq ^ ((row >> 1) & 3)) * 8];
        }
#pragma unroll
        for (int n = 0; n < 4; n++) {
            int row = wc * 64 + n * 16 + ln15;
            bf[n] = *(const s8x8*)&Bs[row * 32 + (kq ^ ((row >> 1) & 3)) * 8];
        }
#pragma unroll
        for (int m = 0; m < 2; m++)
#pragma unroll
            for (int n = 0; n < 4; n++)
                acc[m][n] = __builtin_amdgcn_mfma_f32_16x16x32_bf16(
                    af[m], bf[n], acc[m][n], 0, 0, 0);
        __syncthreads();
    }

    float bcol[4];
#pragma unroll
    for (int n = 0; n < 4; n++)
        bcol[n] = bias[rowB0 + wc * 64 + n * 16 + ln15];
#pragma unroll
    for (int m = 0; m < 2; m++) {
        size_t gr0 = rowA0 + wr * 32 + m * 16 + kq * 4;
#pragma unroll
        for (int n = 0; n < 4; n++) {
            size_t gc = rowB0 + wc * 64 + n * 16 + ln15;
#pragma unroll
            for (int j = 0; j < 4; j++)
                C[(gr0 + j) * 1024 + gc] = acc[m][n][j] + bcol[n];
        }
    }
}

// ---------------------------------------------------------------------------
// Fused t2 + gate (unchanged from round 4 — passing).
// ---------------------------------------------------------------------------
__global__ __launch_bounds__(256) void t2gate(
    const unsigned short* __restrict__ t1, const unsigned short* __restrict__ W2b,
    const float* __restrict__ b2, const float* __restrict__ hs,
    float* __restrict__ gate)
{
    __shared__ __align__(16) short As[16 * 32];
    __shared__ __align__(16) short Bs[64 * 32];
    __shared__ float t2s[16][65];
    __shared__ float hss[16][65];
    const int tid  = threadIdx.x;
    const int wave = tid >> 6;
    const int lane = tid & 63;
    const int ln15 = lane & 15;
    const int kq   = lane >> 4;
    const int m0   = blockIdx.x * 16;

    {
        int r = tid >> 4, c = (tid & 15) * 4;
        float4 v = *(const float4*)(hs + r * 64 + c);
        hss[r][c] = v.x; hss[r][c + 1] = v.y; hss[r][c + 2] = v.z; hss[r][c + 3] = v.w;
    }

    f32x4 acc = (f32x4){0.f, 0.f, 0.f, 0.f};
    for (int k0 = 0; k0 < 1024; k0 += 32) {
        if (tid < 64) {
            int row = tid >> 2, ch = tid & 3;
            int cs = ch ^ ((row >> 1) & 3);
            s8x8 vA = *(const s8x8*)(t1 + (size_t)(m0 + row) * 1024 + k0 + ch * 8);
            *(s8x8*)&As[row * 32 + cs * 8] = vA;
        }
        {
            int row = tid >> 2, ch = tid & 3;
            int cs = ch ^ ((row >> 1) & 3);
            s8x8 vB = *(const s8x8*)(W2b + (size_t)row * 1024 + k0 + ch * 8);
            *(s8x8*)&Bs[row * 32 + cs * 8] = vB;
        }
        __syncthreads();
        int arow = ln15;
        int brow = wave * 16 + ln15;
        s8x8 af = *(const s8x8*)&As[arow * 32 + (kq ^ ((arow >> 1) & 3)) * 8];
        s8x8 bf = *(const s8x8*)&Bs[brow * 32 + (kq ^ ((brow >> 1) & 3)) * 8];
        acc = __builtin_amdgcn_mfma_f32_16x16x32_bf16(af, bf, acc, 0, 0, 0);
        __syncthreads();
    }

#pragma unroll
    for (int j = 0; j < 4; j++)
        t2s[kq * 4 + j][wave * 16 + ln15] = acc[j] + b2[wave * 16 + ln15];
    __syncthreads();

    int r = tid >> 4, hd = tid & 15;
    float s = 0.f;
#pragma unroll 16
    for (int d = 0; d < 64; d++) s += t2s[r][d] * hss[hd][d];
    float mx = s;
    mx = fmaxf(mx, __shfl_xor(mx, 1));
    mx = fmaxf(mx, __shfl_xor(mx, 2));
    mx = fmaxf(mx, __shfl_xor(mx, 4));
    mx = fmaxf(mx, __shfl_xor(mx, 8));
    float e = __expf(s - mx);
    float sum = e;
    sum += __shfl_xor(sum, 1);
    sum += __shfl_xor(sum, 2);
    sum += __shfl_xor(sum, 4);
    sum += __shfl_xor(sum, 8);
    gate[(size_t)(m0 + r) * Hn + hd] = e / sum;
}

// ---------------------------------------------------------------------------
// V transpose (unchanged).
// ---------------------------------------------------------------------------
__global__ __launch_bounds__(256) void transpose_v(
    const unsigned short* __restrict__ vb, unsigned short* __restrict__ vt)
{
    __shared__ unsigned short ts[64][65];
    const int bh = blockIdx.x;
    const int b = bh >> 4, h = bh & 15;
    const int t0 = blockIdx.y * 64;
    const int tid = threadIdx.x;
    {
        int tr = tid >> 2, dq = (tid & 3) * 16;
        const unsigned short* src =
            vb + ((size_t)(t0 + tr) * Bn + b) * En + h * 64 + dq;
        s8x8 a = *(const s8x8*)src;
        s8x8 c = *(const s8x8*)(src + 8);
#pragma unroll
        for (int i = 0; i < 8; i++) {
            ts[tr][dq + i]     = (unsigned short)a[i];
            ts[tr][dq + 8 + i] = (unsigned short)c[i];
        }
    }
    __syncthreads();
    {
        int dr = tid >> 2, tq = (tid & 3) * 16;
        unsigned short* dst = vt + ((size_t)bh * 64 + dr) * Tn + t0 + tq;
        s8x8 o0, o1;
#pragma unroll
        for (int i = 0; i < 8; i++) {
            o0[i] = (short)ts[tq + i][dr];
            o1[i] = (short)ts[tq + 8 + i][dr];
        }
        *(s8x8*)dst = o0;
        *(s8x8*)(dst + 8) = o1;
    }
}

// ---------------------------------------------------------------------------
// MFMA flash attention (unchanged from round 3 — passing).
// ---------------------------------------------------------------------------
__global__ __launch_bounds__(256, 4) void attn_mfma(
    const unsigned short* __restrict__ q, const unsigned short* __restrict__ k,
    const unsigned short* __restrict__ vt, const float* __restrict__ gate,
    unsigned short* __restrict__ o)
{
    __shared__ __align__(16) short Kls[2][64 * 64];
    __shared__ __align__(16) short Vls[2][64 * 64];
    __shared__ __align__(16) short Pls[4][16 * 64];

    const int tid  = threadIdx.x;
    const int w    = tid >> 6;
    const int lane = tid & 63;
    const int ln   = lane & 15;
    const int kq   = lane >> 4;
    const int bh   = blockIdx.x;
    const int b    = bh >> 4;
    const int h    = bh & 15;
    const int qt   = blockIdx.y;

    s8x8 qf[2];
    {
        const int qrow = qt * 64 + w * 16 + ln;
        const unsigned short* src =
            q + ((size_t)qrow * Bn + b) * En + h * 64 + kq * 8;
        qf[0] = *(const s8x8*)(src);
        qf[1] = *(const s8x8*)(src + 32);
    }

    f32x4 O[4];
    float mrun[4], lrun[4];
#pragma unroll
    for (int n = 0; n < 4; n++) O[n] = (f32x4){0.f, 0.f, 0.f, 0.f};
#pragma unroll
    for (int j = 0; j < 4; j++) { mrun[j] = -1e30f; lrun[j] = 0.f; }

    const int srow0 = w * 16 + (lane >> 3);

    auto stage = [&](int bufi, int s0) {
#pragma unroll
        for (int i = 0; i < 2; i++) {
            int row = srow0 + i * 8;
            int c   = (lane & 7) ^ (row & 7);
            const unsigned short* gk =
                k + ((size_t)(s0 + row) * Bn + b) * En + h * 64 + c * 8;
            gload_lds16(gk, &Kls[bufi][w * 1024 + i * 512]);
            const unsigned short* gv =
                vt + ((size_t)bh * 64 + row) * Tn + s0 + c * 8;
            gload_lds16(gv, &Vls[bufi][w * 1024 + i * 512]);
        }
    };

    stage(0, 0);
    asm volatile("s_waitcnt vmcnt(0)" ::: "memory");
    __syncthreads();

    int cur = 0;
    for (int t = 0; t < Tn / 64; t++) {
        if (t + 1 < Tn / 64) stage(cur ^ 1, (t + 1) * 64);

        f32x4 S[4];
#pragma unroll
        for (int n = 0; n < 4; n++) {
            S[n] = (f32x4){0.f, 0.f, 0.f, 0.f};
#pragma unroll
            for (int kk = 0; kk < 2; kk++) {
                int row = n * 16 + ln;
                int cc  = (kk * 4 + kq) ^ (row & 7);
                s8x8 kf = *(const s8x8*)&Kls[cur][row * 64 + cc * 8];
                S[n] = __builtin_amdgcn_mfma_f32_16x16x32_bf16(qf[kk], kf, S[n], 0, 0, 0);
            }
        }

#pragma unroll
        for (int jj = 0; jj < 4; jj++) {
            float rm = fmaxf(fmaxf(S[0][jj], S[1][jj]), fmaxf(S[2][jj], S[3][jj]));
            rm = fmaxf(rm, __shfl_xor(rm, 1));
            rm = fmaxf(rm, __shfl_xor(rm, 2));
            rm = fmaxf(rm, __shfl_xor(rm, 4));
            rm = fmaxf(rm, __shfl_xor(rm, 8));
            float mnew = fmaxf(mrun[jj], rm);
            float fs = __expf(mrun[jj] - mnew);
            float ps = 0.f;
            const int prow = kq * 4 + jj;
#pragma unroll
            for (int n = 0; n < 4; n++) {
                float p = __expf(S[n][jj] - mnew);
                ps += p;
                int col = n * 16 + ln;
                Pls[w][prow * 64 + (((col >> 3) ^ (prow & 7)) << 3) + (col & 7)] =
                    (short)f2bf(p);
            }
            ps += __shfl_xor(ps, 1);
            ps += __shfl_xor(ps, 2);
            ps += __shfl_xor(ps, 4);
            ps += __shfl_xor(ps, 8);
            lrun[jj] = lrun[jj] * fs + ps;
            mrun[jj] = mnew;
#pragma unroll
            for (int n = 0; n < 4; n++) O[n][jj] *= fs;
        }

#pragma unroll
        for (int kk = 0; kk < 2; kk++) {
            int cp = (kk * 4 + kq) ^ (ln & 7);
            s8x8 pa = *(const s8x8*)&Pls[w][ln * 64 + cp * 8];
#pragma unroll
            for (int n = 0; n < 4; n++) {
                int row = n * 16 + ln;
                int cv  = (kk * 4 + kq) ^ (row & 7);
                s8x8 vf = *(const s8x8*)&Vls[cur][row * 64 + cv * 8];
                O[n] = __builtin_amdgcn_mfma_f32_16x16x32_bf16(pa, vf, O[n], 0, 0, 0);
            }
        }

        asm volatile("s_waitcnt vmcnt(0)" ::: "memory");
        __syncthreads();
        cur ^= 1;
    }

#pragma unroll
    for (int jj = 0; jj < 4; jj++) {
        int tq = qt * 64 + w * 16 + kq * 4 + jj;
        size_t m = (size_t)tq * Bn + b;
        float g = gate[m * Hn + h] / lrun[jj];
#pragma unroll
        for (int n = 0; n < 4; n++)
            o[m * En + h * 64 + n * 16 + ln] = f2bf(O[n][jj] * g);
    }
}

// ---------------------------------------------------------------------------
// Workspace layout:
//   Wcat 8MB | W2b 128KB | bcat 16KB | gate 256KB | t1b 8MB | qb 8MB |
//   kb 8MB | vb 8MB | [xb 8MB if ws_size permits]  => 40.4 / 48.4 MB
// Aliases (serialized by stream order): vtb <- t1b (dead after t2gate),
//   Wob <- Wcat (dead after fused_proj), ob <- vb (dead after transpose_v).
// ---------------------------------------------------------------------------
extern "C" void kernel_launch(void* const* d_in, const int* in_sizes, int n_in,
                              void* d_out, int out_size, void* d_ws, size_t ws_size,
                              hipStream_t stream)
{
    const float* x  = (const float*)d_in[0];
    const float* Wq = (const float*)d_in[1];
    const float* bq = (const float*)d_in[2];
    const float* Wk = (const float*)d_in[3];
    const float* bk = (const float*)d_in[4];
    const float* Wv = (const float*)d_in[5];
    const float* bv = (const float*)d_in[6];
    const float* Wo = (const float*)d_in[7];
    const float* bo = (const float*)d_in[8];
    const float* W1 = (const float*)d_in[9];
    const float* b1 = (const float*)d_in[10];
    const float* W2 = (const float*)d_in[11];
    const float* b2 = (const float*)d_in[12];
    const float* hs = (const float*)d_in[13];

    const size_t WELEM = (size_t)En * En;
    unsigned short* Wcat = (unsigned short*)d_ws;            // 4*WELEM
    unsigned short* W2b  = Wcat + 4 * WELEM;                 // 64*1024
    float* bcat = (float*)(W2b + (size_t)SIGn * HIDn);       // 4096 floats
    float* gate = bcat + 4096;                               // 4096*16 floats
    unsigned short* t1b = (unsigned short*)(gate + (size_t)Mn * Hn);
    unsigned short* qb  = t1b + (size_t)Mn * En;
    unsigned short* kb  = qb  + (size_t)Mn * En;
    unsigned short* vb  = kb  + (size_t)Mn * En;
    unsigned short* xb  = vb  + (size_t)Mn * En;             // optional +8MB
    unsigned short* Wob = Wcat;   // alias
    unsigned short* vtb = t1b;    // alias
    unsigned short* ob  = vb;     // alias

    const size_t need_xb =
        (size_t)((char*)(xb + (size_t)Mn * En) - (char*)d_ws);
    const bool pre = ws_size >= need_xb;   // deterministic: ws_size is fixed

    dim3 blk(256);
    const int castGrid = (int)(WELEM / 8 / 256);

    // Weight casts (one dispatch for W1/Wq/Wk/Wv), W2, bias concat.
    cast_w4<<<dim3(castGrid, 4), blk, 0, stream>>>(W1, Wq, Wk, Wv, Wcat);
    cast_bf16<<<32, blk, 0, stream>>>(W2, W2b, (int)((size_t)SIGn * HIDn / 8));
    bias_concat<<<16, blk, 0, stream>>>(b1, bq, bk, bv, bcat);

    // Pre-cast x -> bf16 (removes all VALU cast from fused_proj's hot loop).
    if (pre) {
        cast_bf16<<<dim3((int)((size_t)Mn * En / 8 / 256)), blk, 0, stream>>>(
            x, xb, (int)((size_t)Mn * En / 8));
        fused_proj<1><<<dim3(32, 32), blk, 0, stream>>>(
            x, xb, Wcat, bcat, t1b, qb, kb, vb);
    } else {
        fused_proj<0><<<dim3(32, 32), blk, 0, stream>>>(
            x, xb, Wcat, bcat, t1b, qb, kb, vb);
    }

    // Gate path (fused t2 + logits + softmax).
    t2gate<<<dim3(Mn / 16), blk, 0, stream>>>(t1b, W2b, b2, hs, gate);

    // V -> V^T per (b,h); vtb takes the dead t1b slot.
    transpose_v<<<dim3(Bn * Hn, Tn / 64), blk, 0, stream>>>(vb, vtb);

    // Wo cast into the dead Wcat slot.
    cast_bf16<<<castGrid, blk, 0, stream>>>(Wo, Wob, (int)(WELEM / 8));

    // MFMA flash attention, gate folded in; ob reuses vb's slot.
    attn_mfma<<<dim3(Bn * Hn, Tn / 64), blk, 0, stream>>>(qb, kb, vtb, gate, ob);

    // Output projection into d_out.
    out_proj<<<dim3(En / 128, Mn / 64), blk, 0, stream>>>(ob, Wob, bo, (float*)d_out);
}

// Round 6
// 141.273 us; speedup vs baseline: 4.7352x; 1.1702x over previous
//
#include <hip/hip_runtime.h>

// Problem constants
#define Tn   1024
#define Bn   4
#define En   1024
#define Hn   16
#define HIDn 1024
#define SIGn 64
#define Mn   (Tn * Bn)   // 4096 rows when x viewed as (T*B, E)

typedef short  s8x8  __attribute__((ext_vector_type(8)));   // 8 bf16 (4 VGPRs)
typedef float  f32x4 __attribute__((ext_vector_type(4)));   // MFMA acc

__device__ __forceinline__ float bf2f(unsigned short u) {
    return __uint_as_float(((unsigned int)u) << 16);
}
__device__ __forceinline__ unsigned short f2bf(float f) {
    unsigned int x = __float_as_uint(f);
    unsigned int r = (x + 0x7fffu + ((x >> 16) & 1u)) >> 16;   // RNE
    return (unsigned short)r;
}
// v_exp_f32: D = 2^S0 (CDNA has HW interlocks; plain VALU asm is safe).
__device__ __forceinline__ float exp2asm(float x) {
    float r;
    asm("v_exp_f32 %0, %1" : "=v"(r) : "v"(x));
    return r;
}
// v_cvt_pk_bf16_f32: packs 2 f32 -> 2 bf16 (RNE) in one u32 (lo = src0).
__device__ __forceinline__ unsigned int cvtpk(float a, float b) {
    unsigned int r;
    asm("v_cvt_pk_bf16_f32 %0, %1, %2" : "=v"(r) : "v"(a), "v"(b));
    return r;
}

// global -> LDS direct copy, 16B/lane. LDS dest is wave-uniform base
// (HW writes base + lane*16); global src is per-lane (swizzle goes there).
__device__ __forceinline__ void gload_lds16(const void* g, void* l) {
    __builtin_amdgcn_global_load_lds(
        (const __attribute__((address_space(1))) unsigned int*)g,
        (__attribute__((address_space(3))) unsigned int*)l, 16, 0, 0);
}

// ---------------------------------------------------------------------------
// fp32 -> bf16 cast, 8 elems/thread
// ---------------------------------------------------------------------------
__global__ __launch_bounds__(256) void cast_bf16(
    const float* __restrict__ s, unsigned short* __restrict__ d, int n8)
{
    int i = blockIdx.x * 256 + threadIdx.x;
    if (i >= n8) return;
    const float4* p = (const float4*)(s + (size_t)i * 8);
    float4 a = p[0], b = p[1];
    s8x8 o;
    o[0] = (short)f2bf(a.x); o[1] = (short)f2bf(a.y);
    o[2] = (short)f2bf(a.z); o[3] = (short)f2bf(a.w);
    o[4] = (short)f2bf(b.x); o[5] = (short)f2bf(b.y);
    o[6] = (short)f2bf(b.z); o[7] = (short)f2bf(b.w);
    *(s8x8*)(d + (size_t)i * 8) = o;
}

// 4 weight matrices -> Wcat in one dispatch. grid (WELEM/8/256, 4).
__global__ __launch_bounds__(256) void cast_w4(
    const float* __restrict__ W1, const float* __restrict__ Wq,
    const float* __restrict__ Wk, const float* __restrict__ Wv,
    unsigned short* __restrict__ Wcat)
{
    const size_t WELEM = (size_t)En * En;
    int y = blockIdx.y;
    const float* src = (y == 0) ? W1 : (y == 1) ? Wq : (y == 2) ? Wk : Wv;
    unsigned short* dst = Wcat + (size_t)y * WELEM;
    int i = blockIdx.x * 256 + threadIdx.x;
    const float4* p = (const float4*)(src + (size_t)i * 8);
    float4 a = p[0], b = p[1];
    s8x8 o;
    o[0] = (short)f2bf(a.x); o[1] = (short)f2bf(a.y);
    o[2] = (short)f2bf(a.z); o[3] = (short)f2bf(a.w);
    o[4] = (short)f2bf(b.x); o[5] = (short)f2bf(b.y);
    o[6] = (short)f2bf(b.z); o[7] = (short)f2bf(b.w);
    *(s8x8*)(dst + (size_t)i * 8) = o;
}

// bcat = [b1|bq|bk|bv]  (4096 floats), one dispatch.
__global__ __launch_bounds__(256) void bias_concat(
    const float* __restrict__ b1, const float* __restrict__ bq,
    const float* __restrict__ bk, const float* __restrict__ bv,
    float* __restrict__ bcat)
{
    int i = blockIdx.x * 256 + threadIdx.x;   // 0..4095
    int w = i >> 10;
    const float* s = (w == 0) ? b1 : (w == 1) ? bq : (w == 2) ? bk : bv;
    bcat[i] = s[i & 1023];
}

// ---------------------------------------------------------------------------
// Fused projection GEMM: [t1|q|k|v] = act((x @ Wcat^T + bcat) * scale).
// q's scale folds d^-0.5 AND log2(e) (attention softmax runs in exp2 units).
// ---------------------------------------------------------------------------
template <int PRE>
__global__ __launch_bounds__(256) void fused_proj(
    const float* __restrict__ X, const unsigned short* __restrict__ Xb,
    const unsigned short* __restrict__ Wcat, const float* __restrict__ bcat,
    unsigned short* __restrict__ t1b, unsigned short* __restrict__ qb,
    unsigned short* __restrict__ kb, unsigned short* __restrict__ vb)
{
    __shared__ __align__(16) short As[128 * 32];
    __shared__ __align__(16) short Bs[128 * 32];
    const int tid  = threadIdx.x;
    const int wave = tid >> 6;
    const int lane = tid & 63;
    const int ln15 = lane & 15;
    const int kq   = lane >> 4;
    const int wr   = wave >> 1;
    const int wc   = wave & 1;
    const int bn   = blockIdx.x;
    const int bm   = blockIdx.y;
    const size_t rowA0 = (size_t)bm * 128;
    const size_t rowB0 = (size_t)bn * 128;

    const int lrow   = lane >> 2;
    const int lchunk = lane & 3;

    f32x4 acc[4][4];
#pragma unroll
    for (int m = 0; m < 4; m++)
#pragma unroll
        for (int n = 0; n < 4; n++) acc[m][n] = (f32x4){0.f, 0.f, 0.f, 0.f};

    for (int k0 = 0; k0 < 1024; k0 += 32) {
#pragma unroll
        for (int i = 0; i < 2; i++) {
            int row = wave * 32 + i * 16 + lrow;
            int c   = lchunk ^ ((row >> 1) & 3);
            gload_lds16(Wcat + (rowB0 + row) * 1024 + k0 + c * 8,
                        &Bs[(wave * 32 + i * 16) * 32]);
        }
        if (PRE) {
#pragma unroll
            for (int i = 0; i < 2; i++) {
                int row = wave * 32 + i * 16 + lrow;
                int c   = lchunk ^ ((row >> 1) & 3);
                gload_lds16(Xb + (rowA0 + row) * 1024 + k0 + c * 8,
                            &As[(wave * 32 + i * 16) * 32]);
            }
        } else {
            const int srow = tid >> 1;
            const int scol = (tid & 1) * 16;
            const float4* src = (const float4*)(X + (rowA0 + srow) * 1024 + k0 + scol);
            float4 a = src[0], b = src[1], c4 = src[2], d4 = src[3];
            s8x8 v0, v1;
            v0[0] = (short)f2bf(a.x);  v0[1] = (short)f2bf(a.y);
            v0[2] = (short)f2bf(a.z);  v0[3] = (short)f2bf(a.w);
            v0[4] = (short)f2bf(b.x);  v0[5] = (short)f2bf(b.y);
            v0[6] = (short)f2bf(b.z);  v0[7] = (short)f2bf(b.w);
            v1[0] = (short)f2bf(c4.x); v1[1] = (short)f2bf(c4.y);
            v1[2] = (short)f2bf(c4.z); v1[3] = (short)f2bf(c4.w);
            v1[4] = (short)f2bf(d4.x); v1[5] = (short)f2bf(d4.y);
            v1[6] = (short)f2bf(d4.z); v1[7] = (short)f2bf(d4.w);
            int sw = (srow >> 1) & 3;
            int c0 = (scol >> 3) ^ sw;
            int c1 = ((scol >> 3) + 1) ^ sw;
            *(s8x8*)&As[srow * 32 + c0 * 8] = v0;
            *(s8x8*)&As[srow * 32 + c1 * 8] = v1;
        }
        asm volatile("s_waitcnt vmcnt(0)" ::: "memory");
        __syncthreads();

        s8x8 af[4], bf[4];
#pragma unroll
        for (int m = 0; m < 4; m++) {
            int row = wr * 64 + m * 16 + ln15;
            af[m] = *(const s8x8*)&As[row * 32 + (kq ^ ((row >> 1) & 3)) * 8];
        }
#pragma unroll
        for (int n = 0; n < 4; n++) {
            int row = wc * 64 + n * 16 + ln15;
            bf[n] = *(const s8x8*)&Bs[row * 32 + (kq ^ ((row >> 1) & 3)) * 8];
        }
#pragma unroll
        for (int m = 0; m < 4; m++)
#pragma unroll
            for (int n = 0; n < 4; n++)
                acc[m][n] = __builtin_amdgcn_mfma_f32_16x16x32_bf16(
                    af[m], bf[n], acc[m][n], 0, 0, 0);
        __syncthreads();
    }

    const int which = bn >> 3;
    unsigned short* dst = (which == 0) ? t1b : (which == 1) ? qb
                        : (which == 2) ? kb : vb;
    // q: d^-0.5 * log2(e) so attention softmax can use v_exp_f32 (2^x) directly.
    const float scale = (which == 1) ? 0.18033688011112042f : 1.0f;
    const int   relu  = (which == 0);
    const int   cbase = (bn & 7) * 128;

    float bcol[4];
#pragma unroll
    for (int n = 0; n < 4; n++)
        bcol[n] = bcat[bn * 128 + wc * 64 + n * 16 + ln15];
#pragma unroll
    for (int m = 0; m < 4; m++) {
        size_t gr0 = rowA0 + wr * 64 + m * 16 + kq * 4;
#pragma unroll
        for (int n = 0; n < 4; n++) {
            int gc = cbase + wc * 64 + n * 16 + ln15;
#pragma unroll
            for (int j = 0; j < 4; j++) {
                float vv = acc[m][n][j] + bcol[n];
                if (relu) vv = fmaxf(vv, 0.f);
                vv *= scale;
                dst[(gr0 + j) * 1024 + gc] = f2bf(vv);
            }
        }
    }
}

// ---------------------------------------------------------------------------
// Output projection (unchanged, passing).
// ---------------------------------------------------------------------------
__global__ __launch_bounds__(256) void out_proj(
    const unsigned short* __restrict__ A, const unsigned short* __restrict__ W,
    const float* __restrict__ bias, float* __restrict__ C)
{
    __shared__ __align__(16) short As[64 * 32];
    __shared__ __align__(16) short Bs[128 * 32];
    const int tid  = threadIdx.x;
    const int wave = tid >> 6;
    const int lane = tid & 63;
    const int ln15 = lane & 15;
    const int kq   = lane >> 4;
    const int wr   = wave >> 1;
    const int wc   = wave & 1;
    const size_t rowA0 = (size_t)blockIdx.y * 64;
    const size_t rowB0 = (size_t)blockIdx.x * 128;

    const int lrow   = lane >> 2;
    const int lchunk = lane & 3;

    f32x4 acc[2][4];
#pragma unroll
    for (int m = 0; m < 2; m++)
#pragma unroll
        for (int n = 0; n < 4; n++) acc[m][n] = (f32x4){0.f, 0.f, 0.f, 0.f};

    for (int k0 = 0; k0 < 1024; k0 += 32) {
        {
            int row = wave * 16 + lrow;
            int c   = lchunk ^ ((row >> 1) & 3);
            gload_lds16(A + (rowA0 + row) * 1024 + k0 + c * 8,
                        &As[(wave * 16) * 32]);
        }
#pragma unroll
        for (int i = 0; i < 2; i++) {
            int row = wave * 32 + i * 16 + lrow;
            int c   = lchunk ^ ((row >> 1) & 3);
            gload_lds16(W + (rowB0 + row) * 1024 + k0 + c * 8,
                        &Bs[(wave * 32 + i * 16) * 32]);
        }
        asm volatile("s_waitcnt vmcnt(0)" ::: "memory");
        __syncthreads();

        s8x8 af[2], bf[4];
#pragma unroll
        for (int m = 0; m < 2; m++) {
            int row = wr * 32 + m * 16 + ln15;
            af[m] = *(const s8x8*)&As[row * 32 + (kq ^ ((row >> 1) & 3)) * 8];
        }
#pragma unroll
        for (int n = 0; n < 4; n++) {
            int row = wc * 64 + n * 16 + ln15;
            bf[n] = *(const s8x8*)&Bs[row * 32 + (kq ^ ((row >> 1) & 3)) * 8];
        }
#pragma unroll
        for (int m = 0; m < 2; m++)
#pragma unroll
            for (int n = 0; n < 4; n++)
                acc[m][n] = __builtin_amdgcn_mfma_f32_16x16x32_bf16(
                    af[m], bf[n], acc[m][n], 0, 0, 0);
        __syncthreads();
    }

    float bcol[4];
#pragma unroll
    for (int n = 0; n < 4; n++)
        bcol[n] = bias[rowB0 + wc * 64 + n * 16 + ln15];
#pragma unroll
    for (int m = 0; m < 2; m++) {
        size_t gr0 = rowA0 + wr * 32 + m * 16 + kq * 4;
#pragma unroll
        for (int n = 0; n < 4; n++) {
            size_t gc = rowB0 + wc * 64 + n * 16 + ln15;
#pragma unroll
            for (int j = 0; j < 4; j++)
                C[(gr0 + j) * 1024 + gc] = acc[m][n][j] + bcol[n];
        }
    }
}

// ---------------------------------------------------------------------------
// Fused t2 + gate (unchanged, passing).
// ---------------------------------------------------------------------------
__global__ __launch_bounds__(256) void t2gate(
    const unsigned short* __restrict__ t1, const unsigned short* __restrict__ W2b,
    const float* __restrict__ b2, const float* __restrict__ hs,
    float* __restrict__ gate)
{
    __shared__ __align__(16) short As[16 * 32];
    __shared__ __align__(16) short Bs[64 * 32];
    __shared__ float t2s[16][65];
    __shared__ float hss[16][65];
    const int tid  = threadIdx.x;
    const int wave = tid >> 6;
    const int lane = tid & 63;
    const int ln15 = lane & 15;
    const int kq   = lane >> 4;
    const int m0   = blockIdx.x * 16;

    {
        int r = tid >> 4, c = (tid & 15) * 4;
        float4 v = *(const float4*)(hs + r * 64 + c);
        hss[r][c] = v.x; hss[r][c + 1] = v.y; hss[r][c + 2] = v.z; hss[r][c + 3] = v.w;
    }

    f32x4 acc = (f32x4){0.f, 0.f, 0.f, 0.f};
    for (int k0 = 0; k0 < 1024; k0 += 32) {
        if (tid < 64) {
            int row = tid >> 2, ch = tid & 3;
            int cs = ch ^ ((row >> 1) & 3);
            s8x8 vA = *(const s8x8*)(t1 + (size_t)(m0 + row) * 1024 + k0 + ch * 8);
            *(s8x8*)&As[row * 32 + cs * 8] = vA;
        }
        {
            int row = tid >> 2, ch = tid & 3;
            int cs = ch ^ ((row >> 1) & 3);
            s8x8 vB = *(const s8x8*)(W2b + (size_t)row * 1024 + k0 + ch * 8);
            *(s8x8*)&Bs[row * 32 + cs * 8] = vB;
        }
        __syncthreads();
        int arow = ln15;
        int brow = wave * 16 + ln15;
        s8x8 af = *(const s8x8*)&As[arow * 32 + (kq ^ ((arow >> 1) & 3)) * 8];
        s8x8 bf = *(const s8x8*)&Bs[brow * 32 + (kq ^ ((brow >> 1) & 3)) * 8];
        acc = __builtin_amdgcn_mfma_f32_16x16x32_bf16(af, bf, acc, 0, 0, 0);
        __syncthreads();
    }

#pragma unroll
    for (int j = 0; j < 4; j++)
        t2s[kq * 4 + j][wave * 16 + ln15] = acc[j] + b2[wave * 16 + ln15];
    __syncthreads();

    int r = tid >> 4, hd = tid & 15;
    float s = 0.f;
#pragma unroll 16
    for (int d = 0; d < 64; d++) s += t2s[r][d] * hss[hd][d];
    float mx = s;
    mx = fmaxf(mx, __shfl_xor(mx, 1));
    mx = fmaxf(mx, __shfl_xor(mx, 2));
    mx = fmaxf(mx, __shfl_xor(mx, 4));
    mx = fmaxf(mx, __shfl_xor(mx, 8));
    float e = __expf(s - mx);
    float sum = e;
    sum += __shfl_xor(sum, 1);
    sum += __shfl_xor(sum, 2);
    sum += __shfl_xor(sum, 4);
    sum += __shfl_xor(sum, 8);
    gate[(size_t)(m0 + r) * Hn + hd] = e / sum;
}

// ---------------------------------------------------------------------------
// V transpose (unchanged).
// ---------------------------------------------------------------------------
__global__ __launch_bounds__(256) void transpose_v(
    const unsigned short* __restrict__ vb, unsigned short* __restrict__ vt)
{
    __shared__ unsigned short ts[64][65];
    const int bh = blockIdx.x;
    const int b = bh >> 4, h = bh & 15;
    const int t0 = blockIdx.y * 64;
    const int tid = threadIdx.x;
    {
        int tr = tid >> 2, dq = (tid & 3) * 16;
        const unsigned short* src =
            vb + ((size_t)(t0 + tr) * Bn + b) * En + h * 64 + dq;
        s8x8 a = *(const s8x8*)src;
        s8x8 c = *(const s8x8*)(src + 8);
#pragma unroll
        for (int i = 0; i < 8; i++) {
            ts[tr][dq + i]     = (unsigned short)a[i];
            ts[tr][dq + 8 + i] = (unsigned short)c[i];
        }
    }
    __syncthreads();
    {
        int dr = tid >> 2, tq = (tid & 3) * 16;
        unsigned short* dst = vt + ((size_t)bh * 64 + dr) * Tn + t0 + tq;
        s8x8 o0, o1;
#pragma unroll
        for (int i = 0; i < 8; i++) {
            o0[i] = (short)ts[tq + i][dr];
            o1[i] = (short)ts[tq + 8 + i][dr];
        }
        *(s8x8*)dst = o0;
        *(s8x8*)(dst + 8) = o1;
    }
}

// ---------------------------------------------------------------------------
// MFMA flash attention, swapped-operand + permuted-K form.
//
// QK^T is computed as S^T = mfma(K_frag, Q_frag): C/D col (lane&15) = q-row,
// so each lane owns ONE q-row -> softmax max/sum are in-lane (15 VALU) plus
// 2 shfl_xor across the 4 kq lanes; mrun/lrun are per-lane scalars.
//
// K rows are PERMUTED in LDS (free: permutation folded into the per-lane
// global_load_lds source row): LDS row r=16n+4kq+jj holds K row
// s = 32*(n>>1) + 8*kq + 4*(n&1) + jj.  Then lane (kq,ln)'s 16 P values are
// exactly its PV B-frag k-slots (s = 32kk + 8kq + j) -> P stays in registers;
// 8 v_cvt_pk_bf16_f32 build the B-frags. No P LDS buffer (-8KB -> 5 blk/CU).
//
// PV is swapped too: O^T = mfma(V^T_frag, P^T_frag); V^T staging unchanged.
// Softmax in exp2 units (log2e folded into q). Defer-max THR=8 (T13) skips
// the O-rescale when no row's max grew.
// ---------------------------------------------------------------------------
__global__ __launch_bounds__(256, 5) void attn_mfma(
    const unsigned short* __restrict__ q, const unsigned short* __restrict__ k,
    const unsigned short* __restrict__ vt, const float* __restrict__ gate,
    unsigned short* __restrict__ o)
{
    __shared__ __align__(16) short Kls[2][64 * 64];
    __shared__ __align__(16) short Vls[2][64 * 64];

    const int tid  = threadIdx.x;
    const int w    = tid >> 6;
    const int lane = tid & 63;
    const int ln   = lane & 15;
    const int kq   = lane >> 4;
    const int bh   = blockIdx.x;
    const int b    = bh >> 4;
    const int h    = bh & 15;
    const int qt   = blockIdx.y;

    // Q fragments (B-frag for swapped QK): lane holds Q[q=ln][k=32kk+kq*8+j].
    s8x8 qf[2];
    {
        const int qrow = qt * 64 + w * 16 + ln;
        const unsigned short* src =
            q + ((size_t)qrow * Bn + b) * En + h * 64 + kq * 8;
        qf[0] = *(const s8x8*)(src);
        qf[1] = *(const s8x8*)(src + 32);
    }

    f32x4 OT[4];                 // O^T: lane holds O[q=ln][d=n*16+kq*4+jj]
#pragma unroll
    for (int n = 0; n < 4; n++) OT[n] = (f32x4){0.f, 0.f, 0.f, 0.f};
    float mrun = -1e30f, lrun = 0.f;

    const int srow0 = w * 16 + (lane >> 3);   // LDS staging row, issue 0

    auto stage = [&](int bufi, int s0) {
#pragma unroll
        for (int i = 0; i < 2; i++) {
            int row = srow0 + i * 8;                   // LDS row r
            int c   = (lane & 7) ^ (row & 7);          // bank swizzle (src side)
            // K permutation: global s for LDS row r (n = w is wave-uniform).
            int sK  = 32 * (w >> 1) + 4 * (w & 1)
                    + 8 * ((row >> 2) & 3) + (row & 3);
            const unsigned short* gk =
                k + ((size_t)(s0 + sK) * Bn + b) * En + h * 64 + c * 8;
            gload_lds16(gk, &Kls[bufi][w * 1024 + i * 512]);
            const unsigned short* gv =
                vt + ((size_t)bh * 64 + row) * Tn + s0 + c * 8;
            gload_lds16(gv, &Vls[bufi][w * 1024 + i * 512]);
        }
    };

    stage(0, 0);
    asm volatile("s_waitcnt vmcnt(0)" ::: "memory");
    __syncthreads();

    int cur = 0;
    for (int t = 0; t < Tn / 64; t++) {
        if (t + 1 < Tn / 64) stage(cur ^ 1, (t + 1) * 64);

        // ---- S^T = K' Q^T: lane (kq,ln) gets S[q=ln][s=32(n>>1)+8kq+4(n&1)+jj]
        f32x4 S[4];
#pragma unroll
        for (int n = 0; n < 4; n++) {
            S[n] = (f32x4){0.f, 0.f, 0.f, 0.f};
#pragma unroll
            for (int kk = 0; kk < 2; kk++) {
                int row = n * 16 + ln;
                int cc  = (kk * 4 + kq) ^ (row & 7);
                s8x8 kf = *(const s8x8*)&Kls[cur][row * 64 + cc * 8];
                S[n] = __builtin_amdgcn_mfma_f32_16x16x32_bf16(kf, qf[kk], S[n], 0, 0, 0);
            }
        }

        // ---- in-lane max over this lane's 16 scores + 2 shfl across kq ----
        float rm;
        {
            f32x4 t0 = S[0];
#pragma unroll
            for (int n = 1; n < 4; n++) {
                t0[0] = fmaxf(t0[0], S[n][0]); t0[1] = fmaxf(t0[1], S[n][1]);
                t0[2] = fmaxf(t0[2], S[n][2]); t0[3] = fmaxf(t0[3], S[n][3]);
            }
            rm = fmaxf(fmaxf(t0[0], t0[1]), fmaxf(t0[2], t0[3]));
            rm = fmaxf(rm, __shfl_xor(rm, 16));
            rm = fmaxf(rm, __shfl_xor(rm, 32));
        }

        // ---- defer-max (THR=8 in log2 units) ----
        if (__any(rm > mrun + 8.0f)) {
            float mnew = fmaxf(mrun, rm);
            float fs = exp2asm(mrun - mnew);
            lrun *= fs;
#pragma unroll
            for (int n = 0; n < 4; n++) {
                OT[n][0] *= fs; OT[n][1] *= fs; OT[n][2] *= fs; OT[n][3] *= fs;
            }
            mrun = mnew;
        }

        // ---- P = 2^(S - mrun), in-lane sum, pack B-frags ----
        float ps = 0.f;
#pragma unroll
        for (int n = 0; n < 4; n++) {
            S[n][0] = exp2asm(S[n][0] - mrun); ps += S[n][0];
            S[n][1] = exp2asm(S[n][1] - mrun); ps += S[n][1];
            S[n][2] = exp2asm(S[n][2] - mrun); ps += S[n][2];
            S[n][3] = exp2asm(S[n][3] - mrun); ps += S[n][3];
        }
        ps += __shfl_xor(ps, 16);
        ps += __shfl_xor(ps, 32);
        lrun += ps;

        union { unsigned int u[4]; s8x8 v; } pb[2];
#pragma unroll
        for (int kk = 0; kk < 2; kk++) {
            pb[kk].u[0] = cvtpk(S[2 * kk][0],     S[2 * kk][1]);
            pb[kk].u[1] = cvtpk(S[2 * kk][2],     S[2 * kk][3]);
            pb[kk].u[2] = cvtpk(S[2 * kk + 1][0], S[2 * kk + 1][1]);
            pb[kk].u[3] = cvtpk(S[2 * kk + 1][2], S[2 * kk + 1][3]);
        }

        // ---- O^T += V^T P^T ----
#pragma unroll
        for (int kk = 0; kk < 2; kk++) {
#pragma unroll
            for (int n = 0; n < 4; n++) {
                int row = n * 16 + ln;
                int cv  = (kk * 4 + kq) ^ (row & 7);
                s8x8 vf = *(const s8x8*)&Vls[cur][row * 64 + cv * 8];
                OT[n] = __builtin_amdgcn_mfma_f32_16x16x32_bf16(vf, pb[kk].v, OT[n], 0, 0, 0);
            }
        }

        asm volatile("s_waitcnt vmcnt(0)" ::: "memory");
        __syncthreads();
        cur ^= 1;
    }

    // ---- epilogue: one q-row per lane; gate+normalize; packed 8B stores ----
    {
        int tq = qt * 64 + w * 16 + ln;
        size_t m = (size_t)tq * Bn + b;
        float g = gate[m * Hn + h] / lrun;
        unsigned short* dst = o + m * En + h * 64;
#pragma unroll
        for (int n = 0; n < 4; n++) {
            int d0 = n * 16 + kq * 4;
            uint2 pkv;
            pkv.x = cvtpk(OT[n][0] * g, OT[n][1] * g);
            pkv.y = cvtpk(OT[n][2] * g, OT[n][3] * g);
            *(uint2*)(dst + d0) = pkv;
        }
    }
}

// ---------------------------------------------------------------------------
// Workspace layout:
//   Wcat 8MB | W2b 128KB | bcat 16KB | gate 256KB | t1b 8MB | qb 8MB |
//   kb 8MB | vb 8MB | [xb 8MB if ws_size permits]  => 40.4 / 48.4 MB
// Aliases (serialized by stream order): vtb <- t1b (dead after t2gate),
//   Wob <- Wcat (dead after fused_proj), ob <- vb (dead after transpose_v).
// ---------------------------------------------------------------------------
extern "C" void kernel_launch(void* const* d_in, const int* in_sizes, int n_in,
                              void* d_out, int out_size, void* d_ws, size_t ws_size,
                              hipStream_t stream)
{
    const float* x  = (const float*)d_in[0];
    const float* Wq = (const float*)d_in[1];
    const float* bq = (const float*)d_in[2];
    const float* Wk = (const float*)d_in[3];
    const float* bk = (const float*)d_in[4];
    const float* Wv = (const float*)d_in[5];
    const float* bv = (const float*)d_in[6];
    const float* Wo = (const float*)d_in[7];
    const float* bo = (const float*)d_in[8];
    const float* W1 = (const float*)d_in[9];
    const float* b1 = (const float*)d_in[10];
    const float* W2 = (const float*)d_in[11];
    const float* b2 = (const float*)d_in[12];
    const float* hs = (const float*)d_in[13];

    const size_t WELEM = (size_t)En * En;
    unsigned short* Wcat = (unsigned short*)d_ws;            // 4*WELEM
    unsigned short* W2b  = Wcat + 4 * WELEM;                 // 64*1024
    float* bcat = (float*)(W2b + (size_t)SIGn * HIDn);       // 4096 floats
    float* gate = bcat + 4096;                               // 4096*16 floats
    unsigned short* t1b = (unsigned short*)(gate + (size_t)Mn * Hn);
    unsigned short* qb  = t1b + (size_t)Mn * En;
    unsigned short* kb  = qb  + (size_t)Mn * En;
    unsigned short* vb  = kb  + (size_t)Mn * En;
    unsigned short* xb  = vb  + (size_t)Mn * En;             // optional +8MB
    unsigned short* Wob = Wcat;   // alias
    unsigned short* vtb = t1b;    // alias
    unsigned short* ob  = vb;     // alias

    const size_t need_xb =
        (size_t)((char*)(xb + (size_t)Mn * En) - (char*)d_ws);
    const bool pre = ws_size >= need_xb;   // deterministic: ws_size is fixed

    dim3 blk(256);
    const int castGrid = (int)(WELEM / 8 / 256);

    cast_w4<<<dim3(castGrid, 4), blk, 0, stream>>>(W1, Wq, Wk, Wv, Wcat);
    cast_bf16<<<32, blk, 0, stream>>>(W2, W2b, (int)((size_t)SIGn * HIDn / 8));
    bias_concat<<<16, blk, 0, stream>>>(b1, bq, bk, bv, bcat);

    if (pre) {
        cast_bf16<<<dim3((int)((size_t)Mn * En / 8 / 256)), blk, 0, stream>>>(
            x, xb, (int)((size_t)Mn * En / 8));
        fused_proj<1><<<dim3(32, 32), blk, 0, stream>>>(
            x, xb, Wcat, bcat, t1b, qb, kb, vb);
    } else {
        fused_proj<0><<<dim3(32, 32), blk, 0, stream>>>(
            x, xb, Wcat, bcat, t1b, qb, kb, vb);
    }

    t2gate<<<dim3(Mn / 16), blk, 0, stream>>>(t1b, W2b, b2, hs, gate);

    transpose_v<<<dim3(Bn * Hn, Tn / 64), blk, 0, stream>>>(vb, vtb);

    cast_bf16<<<castGrid, blk, 0, stream>>>(Wo, Wob, (int)(WELEM / 8));

    attn_mfma<<<dim3(Bn * Hn, Tn / 64), blk, 0, stream>>>(qb, kb, vtb, gate, ob);

    out_proj<<<dim3(En / 128, Mn / 64), blk, 0, stream>>>(ob, Wob, bo, (float*)d_out);
}

// Round 7
// 135.290 us; speedup vs baseline: 4.9446x; 1.0442x over previous
//
#include <hip/hip_runtime.h>

// Problem constants
#define Tn   1024
#define Bn   4
#define En   1024
#define Hn   16
#define HIDn 1024
#define SIGn 64
#define Mn   (Tn * Bn)   // 4096 rows when x viewed as (T*B, E)

typedef short  s8x8  __attribute__((ext_vector_type(8)));   // 8 bf16 (4 VGPRs)
typedef float  f32x4 __attribute__((ext_vector_type(4)));   // MFMA acc

__device__ __forceinline__ float bf2f(unsigned short u) {
    return __uint_as_float(((unsigned int)u) << 16);
}
__device__ __forceinline__ unsigned short f2bf(float f) {
    unsigned int x = __float_as_uint(f);
    unsigned int r = (x + 0x7fffu + ((x >> 16) & 1u)) >> 16;   // RNE
    return (unsigned short)r;
}
// v_exp_f32: D = 2^S0.
__device__ __forceinline__ float exp2asm(float x) {
    float r;
    asm("v_exp_f32 %0, %1" : "=v"(r) : "v"(x));
    return r;
}
// v_cvt_pk_bf16_f32: packs 2 f32 -> 2 bf16 (RNE) in one u32 (lo = src0).
__device__ __forceinline__ unsigned int cvtpk(float a, float b) {
    unsigned int r;
    asm("v_cvt_pk_bf16_f32 %0, %1, %2" : "=v"(r) : "v"(a), "v"(b));
    return r;
}

// global -> LDS direct copy, 16B/lane. LDS dest is wave-uniform base
// (HW writes base + lane*16); global src is per-lane (swizzle goes there).
__device__ __forceinline__ void gload_lds16(const void* g, void* l) {
    __builtin_amdgcn_global_load_lds(
        (const __attribute__((address_space(1))) unsigned int*)g,
        (__attribute__((address_space(3))) unsigned int*)l, 16, 0, 0);
}

// ---------------------------------------------------------------------------
// fp32 -> bf16 cast, 8 elems/thread
// ---------------------------------------------------------------------------
__global__ __launch_bounds__(256) void cast_bf16(
    const float* __restrict__ s, unsigned short* __restrict__ d, int n8)
{
    int i = blockIdx.x * 256 + threadIdx.x;
    if (i >= n8) return;
    const float4* p = (const float4*)(s + (size_t)i * 8);
    float4 a = p[0], b = p[1];
    s8x8 o;
    o[0] = (short)f2bf(a.x); o[1] = (short)f2bf(a.y);
    o[2] = (short)f2bf(a.z); o[3] = (short)f2bf(a.w);
    o[4] = (short)f2bf(b.x); o[5] = (short)f2bf(b.y);
    o[6] = (short)f2bf(b.z); o[7] = (short)f2bf(b.w);
    *(s8x8*)(d + (size_t)i * 8) = o;
}

// 4 weight matrices -> Wcat in one dispatch. grid (WELEM/8/256, 4).
__global__ __launch_bounds__(256) void cast_w4(
    const float* __restrict__ W1, const float* __restrict__ Wq,
    const float* __restrict__ Wk, const float* __restrict__ Wv,
    unsigned short* __restrict__ Wcat)
{
    const size_t WELEM = (size_t)En * En;
    int y = blockIdx.y;
    const float* src = (y == 0) ? W1 : (y == 1) ? Wq : (y == 2) ? Wk : Wv;
    unsigned short* dst = Wcat + (size_t)y * WELEM;
    int i = blockIdx.x * 256 + threadIdx.x;
    const float4* p = (const float4*)(src + (size_t)i * 8);
    float4 a = p[0], b = p[1];
    s8x8 o;
    o[0] = (short)f2bf(a.x); o[1] = (short)f2bf(a.y);
    o[2] = (short)f2bf(a.z); o[3] = (short)f2bf(a.w);
    o[4] = (short)f2bf(b.x); o[5] = (short)f2bf(b.y);
    o[6] = (short)f2bf(b.z); o[7] = (short)f2bf(b.w);
    *(s8x8*)(dst + (size_t)i * 8) = o;
}

// bcat = [b1|bq|bk|bv]  (4096 floats), one dispatch.
__global__ __launch_bounds__(256) void bias_concat(
    const float* __restrict__ b1, const float* __restrict__ bq,
    const float* __restrict__ bk, const float* __restrict__ bv,
    float* __restrict__ bcat)
{
    int i = blockIdx.x * 256 + threadIdx.x;   // 0..4095
    int w = i >> 10;
    const float* s = (w == 0) ? b1 : (w == 1) ? bq : (w == 2) ? bk : bv;
    bcat[i] = s[i & 1023];
}

// ---------------------------------------------------------------------------
// Fused projection GEMM: [t1|q|k|v] = act((x @ Wcat^T + bcat) * scale).
// BK=64 (barrier count halved vs round 6: 16 iters, 32 MFMA/wave/iter).
// LDS rows = 64 bf16 = 128B = 8 chunks; swizzle chunk ^= row&7 (0-conflict,
// proven in attn). Both operands via global_load_lds (source-side swizzle).
// XCD-aware bijective block swizzle (1024 blocks % 8 == 0).
// ---------------------------------------------------------------------------
template <int PRE>
__global__ __launch_bounds__(256) void fused_proj(
    const float* __restrict__ X, const unsigned short* __restrict__ Xb,
    const unsigned short* __restrict__ Wcat, const float* __restrict__ bcat,
    unsigned short* __restrict__ t1b, unsigned short* __restrict__ qb,
    unsigned short* __restrict__ kb, unsigned short* __restrict__ vb)
{
    __shared__ __align__(16) short As[128 * 64];   // 16 KB
    __shared__ __align__(16) short Bs[128 * 64];   // 16 KB
    const int tid   = threadIdx.x;
    const int wave  = tid >> 6;
    const int lane  = tid & 63;
    const int ln15  = lane & 15;
    const int kq    = lane >> 4;
    const int wr    = wave >> 1;
    const int wc    = wave & 1;
    const int lrow8 = lane >> 3;   // 0..7
    const int lch   = lane & 7;    // stored chunk

    // XCD swizzle: each XCD gets 128 consecutive remapped ids (bijective).
    const int wgid = blockIdx.y * 32 + blockIdx.x;
    const int swz  = (wgid & 7) * 128 + (wgid >> 3);
    const int bn   = swz & 31;
    const int bm   = swz >> 5;
    const size_t rowA0 = (size_t)bm * 128;
    const size_t rowB0 = (size_t)bn * 128;

    f32x4 acc[4][4];
#pragma unroll
    for (int m = 0; m < 4; m++)
#pragma unroll
        for (int n = 0; n < 4; n++) acc[m][n] = (f32x4){0.f, 0.f, 0.f, 0.f};

    for (int k0 = 0; k0 < 1024; k0 += 64) {
        // ---- B tile 128x64: 4 issues/wave ----
#pragma unroll
        for (int i = 0; i < 4; i++) {
            int row = wave * 32 + i * 8 + lrow8;
            int cg  = lch ^ (row & 7);
            gload_lds16(Wcat + (rowB0 + row) * 1024 + k0 + cg * 8,
                        &Bs[(wave * 32 + i * 8) * 64]);
        }
        // ---- A tile 128x64 ----
        if (PRE) {
#pragma unroll
            for (int i = 0; i < 4; i++) {
                int row = wave * 32 + i * 8 + lrow8;
                int cg  = lch ^ (row & 7);
                gload_lds16(Xb + (rowA0 + row) * 1024 + k0 + cg * 8,
                            &As[(wave * 32 + i * 8) * 64]);
            }
        } else {
            const int srow = tid >> 1;          // 0..127
            const int scol = (tid & 1) * 32;    // 0 or 32 elems
            const float4* src =
                (const float4*)(X + (rowA0 + srow) * 1024 + k0 + scol);
#pragma unroll
            for (int j = 0; j < 4; j++) {
                float4 a = src[2 * j], b = src[2 * j + 1];
                s8x8 v;
                v[0] = (short)f2bf(a.x); v[1] = (short)f2bf(a.y);
                v[2] = (short)f2bf(a.z); v[3] = (short)f2bf(a.w);
                v[4] = (short)f2bf(b.x); v[5] = (short)f2bf(b.y);
                v[6] = (short)f2bf(b.z); v[7] = (short)f2bf(b.w);
                int cs = ((scol >> 3) + j) ^ (srow & 7);
                *(s8x8*)&As[srow * 64 + cs * 8] = v;
            }
        }
        asm volatile("s_waitcnt vmcnt(0)" ::: "memory");
        __syncthreads();

#pragma unroll
        for (int kk = 0; kk < 2; kk++) {
            s8x8 af[4], bf4[4];
#pragma unroll
            for (int m = 0; m < 4; m++) {
                int row = wr * 64 + m * 16 + ln15;
                af[m] = *(const s8x8*)&As[row * 64 + (((kk * 4 + kq) ^ (row & 7)) * 8)];
            }
#pragma unroll
            for (int n = 0; n < 4; n++) {
                int row = wc * 64 + n * 16 + ln15;
                bf4[n] = *(const s8x8*)&Bs[row * 64 + (((kk * 4 + kq) ^ (row & 7)) * 8)];
            }
#pragma unroll
            for (int m = 0; m < 4; m++)
#pragma unroll
                for (int n = 0; n < 4; n++)
                    acc[m][n] = __builtin_amdgcn_mfma_f32_16x16x32_bf16(
                        af[m], bf4[n], acc[m][n], 0, 0, 0);
        }
        __syncthreads();
    }

    const int which = bn >> 3;
    unsigned short* dst = (which == 0) ? t1b : (which == 1) ? qb
                        : (which == 2) ? kb : vb;
    // q: d^-0.5 * log2(e) so attention softmax can use v_exp_f32 (2^x) directly.
    const float scale = (which == 1) ? 0.18033688011112042f : 1.0f;
    const int   relu  = (which == 0);
    const int   cbase = (bn & 7) * 128;

    float bcol[4];
#pragma unroll
    for (int n = 0; n < 4; n++)
        bcol[n] = bcat[bn * 128 + wc * 64 + n * 16 + ln15];
#pragma unroll
    for (int m = 0; m < 4; m++) {
        size_t gr0 = rowA0 + wr * 64 + m * 16 + kq * 4;
#pragma unroll
        for (int n = 0; n < 4; n++) {
            int gc = cbase + wc * 64 + n * 16 + ln15;
#pragma unroll
            for (int j = 0; j < 4; j++) {
                float vv = acc[m][n][j] + bcol[n];
                if (relu) vv = fmaxf(vv, 0.f);
                vv *= scale;
                dst[(gr0 + j) * 1024 + gc] = f2bf(vv);
            }
        }
    }
}

// ---------------------------------------------------------------------------
// Output projection: d_out = ob @ Wo^T + bo. BK=64, tile 64x128.
// XCD swizzle (512 % 8 == 0): one XCD's 64 blocks share 8 A-panels + all of
// Wo-bf16 (2MB, fits the 4MB per-XCD L2).
// ---------------------------------------------------------------------------
__global__ __launch_bounds__(256) void out_proj(
    const unsigned short* __restrict__ A, const unsigned short* __restrict__ W,
    const float* __restrict__ bias, float* __restrict__ C)
{
    __shared__ __align__(16) short As[64 * 64];    // 8 KB
    __shared__ __align__(16) short Bs[128 * 64];   // 16 KB
    const int tid   = threadIdx.x;
    const int wave  = tid >> 6;
    const int lane  = tid & 63;
    const int ln15  = lane & 15;
    const int kq    = lane >> 4;
    const int wr    = wave >> 1;
    const int wc    = wave & 1;
    const int lrow8 = lane >> 3;
    const int lch   = lane & 7;

    const int wgid = blockIdx.y * 8 + blockIdx.x;      // grid (8, 64)
    const int swz  = (wgid & 7) * 64 + (wgid >> 3);
    const int bx   = swz & 7;
    const int by   = swz >> 3;
    const size_t rowA0 = (size_t)by * 64;
    const size_t rowB0 = (size_t)bx * 128;

    f32x4 acc[2][4];
#pragma unroll
    for (int m = 0; m < 2; m++)
#pragma unroll
        for (int n = 0; n < 4; n++) acc[m][n] = (f32x4){0.f, 0.f, 0.f, 0.f};

    for (int k0 = 0; k0 < 1024; k0 += 64) {
#pragma unroll
        for (int i = 0; i < 2; i++) {   // A tile 64x64: 2 issues/wave
            int row = wave * 16 + i * 8 + lrow8;
            int cg  = lch ^ (row & 7);
            gload_lds16(A + (rowA0 + row) * 1024 + k0 + cg * 8,
                        &As[(wave * 16 + i * 8) * 64]);
        }
#pragma unroll
        for (int i = 0; i < 4; i++) {   // B tile 128x64: 4 issues/wave
            int row = wave * 32 + i * 8 + lrow8;
            int cg  = lch ^ (row & 7);
            gload_lds16(W + (rowB0 + row) * 1024 + k0 + cg * 8,
                        &Bs[(wave * 32 + i * 8) * 64]);
        }
        asm volatile("s_waitcnt vmcnt(0)" ::: "memory");
        __syncthreads();

#pragma unroll
        for (int kk = 0; kk < 2; kk++) {
            s8x8 af[2], bf4[4];
#pragma unroll
            for (int m = 0; m < 2; m++) {
                int row = wr * 32 + m * 16 + ln15;
                af[m] = *(const s8x8*)&As[row * 64 + (((kk * 4 + kq) ^ (row & 7)) * 8)];
            }
#pragma unroll
            for (int n = 0; n < 4; n++) {
                int row = wc * 64 + n * 16 + ln15;
                bf4[n] = *(const s8x8*)&Bs[row * 64 + (((kk * 4 + kq) ^ (row & 7)) * 8)];
            }
#pragma unroll
            for (int m = 0; m < 2; m++)
#pragma unroll
                for (int n = 0; n < 4; n++)
                    acc[m][n] = __builtin_amdgcn_mfma_f32_16x16x32_bf16(
                        af[m], bf4[n], acc[m][n], 0, 0, 0);
        }
        __syncthreads();
    }

    float bcol[4];
#pragma unroll
    for (int n = 0; n < 4; n++)
        bcol[n] = bias[rowB0 + wc * 64 + n * 16 + ln15];
#pragma unroll
    for (int m = 0; m < 2; m++) {
        size_t gr0 = rowA0 + wr * 32 + m * 16 + kq * 4;
#pragma unroll
        for (int n = 0; n < 4; n++) {
            size_t gc = rowB0 + wc * 64 + n * 16 + ln15;
#pragma unroll
            for (int j = 0; j < 4; j++)
                C[(gr0 + j) * 1024 + gc] = acc[m][n][j] + bcol[n];
        }
    }
}

// ---------------------------------------------------------------------------
// Fused t2 + gate. BK=64, staging via global_load_lds (t1/W2 both bf16).
// Per block: 16 rows; t2 = t1 @ W2b^T + b2 (MFMA), logits = t2 @ hs^T,
// softmax over 16 heads -> gate. Grid 256 blocks.
// ---------------------------------------------------------------------------
__global__ __launch_bounds__(256) void t2gate(
    const unsigned short* __restrict__ t1, const unsigned short* __restrict__ W2b,
    const float* __restrict__ b2, const float* __restrict__ hs,
    float* __restrict__ gate)
{
    __shared__ __align__(16) short As[16 * 64];    // 2 KB
    __shared__ __align__(16) short Bs[64 * 64];    // 8 KB
    __shared__ float t2s[16][65];
    __shared__ float hss[16][65];
    const int tid   = threadIdx.x;
    const int wave  = tid >> 6;
    const int lane  = tid & 63;
    const int ln15  = lane & 15;
    const int kq    = lane >> 4;
    const int lrow8 = lane >> 3;
    const int lch   = lane & 7;
    const int m0    = blockIdx.x * 16;

    {
        int r = tid >> 4, c = (tid & 15) * 4;
        float4 v = *(const float4*)(hs + r * 64 + c);
        hss[r][c] = v.x; hss[r][c + 1] = v.y; hss[r][c + 2] = v.z; hss[r][c + 3] = v.w;
    }

    f32x4 acc = (f32x4){0.f, 0.f, 0.f, 0.f};
    for (int k0 = 0; k0 < 1024; k0 += 64) {
        if (wave < 2) {                 // A tile 16x64: waves 0-1, 1 issue
            int row = wave * 8 + lrow8;
            int cg  = lch ^ (row & 7);
            gload_lds16(t1 + (size_t)(m0 + row) * 1024 + k0 + cg * 8,
                        &As[(wave * 8) * 64]);
        }
#pragma unroll
        for (int i = 0; i < 2; i++) {   // B tile 64x64: 2 issues/wave
            int row = wave * 16 + i * 8 + lrow8;
            int cg  = lch ^ (row & 7);
            gload_lds16(W2b + (size_t)row * 1024 + k0 + cg * 8,
                        &Bs[(wave * 16 + i * 8) * 64]);
        }
        asm volatile("s_waitcnt vmcnt(0)" ::: "memory");
        __syncthreads();

#pragma unroll
        for (int kk = 0; kk < 2; kk++) {
            int arow = ln15;
            int brow = wave * 16 + ln15;
            s8x8 af = *(const s8x8*)&As[arow * 64 + (((kk * 4 + kq) ^ (arow & 7)) * 8)];
            s8x8 bf = *(const s8x8*)&Bs[brow * 64 + (((kk * 4 + kq) ^ (brow & 7)) * 8)];
            acc = __builtin_amdgcn_mfma_f32_16x16x32_bf16(af, bf, acc, 0, 0, 0);
        }
        __syncthreads();
    }

#pragma unroll
    for (int j = 0; j < 4; j++)
        t2s[kq * 4 + j][wave * 16 + ln15] = acc[j] + b2[wave * 16 + ln15];
    __syncthreads();

    int r = tid >> 4, hd = tid & 15;
    float s = 0.f;
#pragma unroll 16
    for (int d = 0; d < 64; d++) s += t2s[r][d] * hss[hd][d];
    float mx = s;
    mx = fmaxf(mx, __shfl_xor(mx, 1));
    mx = fmaxf(mx, __shfl_xor(mx, 2));
    mx = fmaxf(mx, __shfl_xor(mx, 4));
    mx = fmaxf(mx, __shfl_xor(mx, 8));
    float e = __expf(s - mx);
    float sum = e;
    sum += __shfl_xor(sum, 1);
    sum += __shfl_xor(sum, 2);
    sum += __shfl_xor(sum, 4);
    sum += __shfl_xor(sum, 8);
    gate[(size_t)(m0 + r) * Hn + hd] = e / sum;
}

// ---------------------------------------------------------------------------
// V transpose (unchanged).
// ---------------------------------------------------------------------------
__global__ __launch_bounds__(256) void transpose_v(
    const unsigned short* __restrict__ vb, unsigned short* __restrict__ vt)
{
    __shared__ unsigned short ts[64][65];
    const int bh = blockIdx.x;
    const int b = bh >> 4, h = bh & 15;
    const int t0 = blockIdx.y * 64;
    const int tid = threadIdx.x;
    {
        int tr = tid >> 2, dq = (tid & 3) * 16;
        const unsigned short* src =
            vb + ((size_t)(t0 + tr) * Bn + b) * En + h * 64 + dq;
        s8x8 a = *(const s8x8*)src;
        s8x8 c = *(const s8x8*)(src + 8);
#pragma unroll
        for (int i = 0; i < 8; i++) {
            ts[tr][dq + i]     = (unsigned short)a[i];
            ts[tr][dq + 8 + i] = (unsigned short)c[i];
        }
    }
    __syncthreads();
    {
        int dr = tid >> 2, tq = (tid & 3) * 16;
        unsigned short* dst = vt + ((size_t)bh * 64 + dr) * Tn + t0 + tq;
        s8x8 o0, o1;
#pragma unroll
        for (int i = 0; i < 8; i++) {
            o0[i] = (short)ts[tq + i][dr];
            o1[i] = (short)ts[tq + 8 + i][dr];
        }
        *(s8x8*)dst = o0;
        *(s8x8*)(dst + 8) = o1;
    }
}

// ---------------------------------------------------------------------------
// MFMA flash attention, swapped-operand + permuted-K form (round 6, passing)
// + T5 setprio around the MFMA clusters.
// ---------------------------------------------------------------------------
__global__ __launch_bounds__(256, 5) void attn_mfma(
    const unsigned short* __restrict__ q, const unsigned short* __restrict__ k,
    const unsigned short* __restrict__ vt, const float* __restrict__ gate,
    unsigned short* __restrict__ o)
{
    __shared__ __align__(16) short Kls[2][64 * 64];
    __shared__ __align__(16) short Vls[2][64 * 64];

    const int tid  = threadIdx.x;
    const int w    = tid >> 6;
    const int lane = tid & 63;
    const int ln   = lane & 15;
    const int kq   = lane >> 4;
    const int bh   = blockIdx.x;
    const int b    = bh >> 4;
    const int h    = bh & 15;
    const int qt   = blockIdx.y;

    s8x8 qf[2];
    {
        const int qrow = qt * 64 + w * 16 + ln;
        const unsigned short* src =
            q + ((size_t)qrow * Bn + b) * En + h * 64 + kq * 8;
        qf[0] = *(const s8x8*)(src);
        qf[1] = *(const s8x8*)(src + 32);
    }

    f32x4 OT[4];
#pragma unroll
    for (int n = 0; n < 4; n++) OT[n] = (f32x4){0.f, 0.f, 0.f, 0.f};
    float mrun = -1e30f, lrun = 0.f;

    const int srow0 = w * 16 + (lane >> 3);

    auto stage = [&](int bufi, int s0) {
#pragma unroll
        for (int i = 0; i < 2; i++) {
            int row = srow0 + i * 8;
            int c   = (lane & 7) ^ (row & 7);
            int sK  = 32 * (w >> 1) + 4 * (w & 1)
                    + 8 * ((row >> 2) & 3) + (row & 3);
            const unsigned short* gk =
                k + ((size_t)(s0 + sK) * Bn + b) * En + h * 64 + c * 8;
            gload_lds16(gk, &Kls[bufi][w * 1024 + i * 512]);
            const unsigned short* gv =
                vt + ((size_t)bh * 64 + row) * Tn + s0 + c * 8;
            gload_lds16(gv, &Vls[bufi][w * 1024 + i * 512]);
        }
    };

    stage(0, 0);
    asm volatile("s_waitcnt vmcnt(0)" ::: "memory");
    __syncthreads();

    int cur = 0;
    for (int t = 0; t < Tn / 64; t++) {
        if (t + 1 < Tn / 64) stage(cur ^ 1, (t + 1) * 64);

        f32x4 S[4];
        __builtin_amdgcn_s_setprio(1);
#pragma unroll
        for (int n = 0; n < 4; n++) {
            S[n] = (f32x4){0.f, 0.f, 0.f, 0.f};
#pragma unroll
            for (int kk = 0; kk < 2; kk++) {
                int row = n * 16 + ln;
                int cc  = (kk * 4 + kq) ^ (row & 7);
                s8x8 kf = *(const s8x8*)&Kls[cur][row * 64 + cc * 8];
                S[n] = __builtin_amdgcn_mfma_f32_16x16x32_bf16(kf, qf[kk], S[n], 0, 0, 0);
            }
        }
        __builtin_amdgcn_s_setprio(0);

        float rm;
        {
            f32x4 t0 = S[0];
#pragma unroll
            for (int n = 1; n < 4; n++) {
                t0[0] = fmaxf(t0[0], S[n][0]); t0[1] = fmaxf(t0[1], S[n][1]);
                t0[2] = fmaxf(t0[2], S[n][2]); t0[3] = fmaxf(t0[3], S[n][3]);
            }
            rm = fmaxf(fmaxf(t0[0], t0[1]), fmaxf(t0[2], t0[3]));
            rm = fmaxf(rm, __shfl_xor(rm, 16));
            rm = fmaxf(rm, __shfl_xor(rm, 32));
        }

        if (__any(rm > mrun + 8.0f)) {
            float mnew = fmaxf(mrun, rm);
            float fs = exp2asm(mrun - mnew);
            lrun *= fs;
#pragma unroll
            for (int n = 0; n < 4; n++) {
                OT[n][0] *= fs; OT[n][1] *= fs; OT[n][2] *= fs; OT[n][3] *= fs;
            }
            mrun = mnew;
        }

        float ps = 0.f;
#pragma unroll
        for (int n = 0; n < 4; n++) {
            S[n][0] = exp2asm(S[n][0] - mrun); ps += S[n][0];
            S[n][1] = exp2asm(S[n][1] - mrun); ps += S[n][1];
            S[n][2] = exp2asm(S[n][2] - mrun); ps += S[n][2];
            S[n][3] = exp2asm(S[n][3] - mrun); ps += S[n][3];
        }
        ps += __shfl_xor(ps, 16);
        ps += __shfl_xor(ps, 32);
        lrun += ps;

        union { unsigned int u[4]; s8x8 v; } pb[2];
#pragma unroll
        for (int kk = 0; kk < 2; kk++) {
            pb[kk].u[0] = cvtpk(S[2 * kk][0],     S[2 * kk][1]);
            pb[kk].u[1] = cvtpk(S[2 * kk][2],     S[2 * kk][3]);
            pb[kk].u[2] = cvtpk(S[2 * kk + 1][0], S[2 * kk + 1][1]);
            pb[kk].u[3] = cvtpk(S[2 * kk + 1][2], S[2 * kk + 1][3]);
        }

        __builtin_amdgcn_s_setprio(1);
#pragma unroll
        for (int kk = 0; kk < 2; kk++) {
#pragma unroll
            for (int n = 0; n < 4; n++) {
                int row = n * 16 + ln;
                int cv  = (kk * 4 + kq) ^ (row & 7);
                s8x8 vf = *(const s8x8*)&Vls[cur][row * 64 + cv * 8];
                OT[n] = __builtin_amdgcn_mfma_f32_16x16x32_bf16(vf, pb[kk].v, OT[n], 0, 0, 0);
            }
        }
        __builtin_amdgcn_s_setprio(0);

        asm volatile("s_waitcnt vmcnt(0)" ::: "memory");
        __syncthreads();
        cur ^= 1;
    }

    {
        int tq = qt * 64 + w * 16 + ln;
        size_t m = (size_t)tq * Bn + b;
        float g = gate[m * Hn + h] / lrun;
        unsigned short* dst = o + m * En + h * 64;
#pragma unroll
        for (int n = 0; n < 4; n++) {
            int d0 = n * 16 + kq * 4;
            uint2 pkv;
            pkv.x = cvtpk(OT[n][0] * g, OT[n][1] * g);
            pkv.y = cvtpk(OT[n][2] * g, OT[n][3] * g);
            *(uint2*)(dst + d0) = pkv;
        }
    }
}

// ---------------------------------------------------------------------------
// Workspace layout:
//   Wcat 8MB | W2b 128KB | bcat 16KB | gate 256KB | t1b 8MB | qb 8MB |
//   kb 8MB | vb 8MB | [xb 8MB if ws_size permits]  => 40.4 / 48.4 MB
// Aliases (serialized by stream order): vtb <- t1b (dead after t2gate),
//   Wob <- Wcat (dead after fused_proj), ob <- vb (dead after transpose_v).
// ---------------------------------------------------------------------------
extern "C" void kernel_launch(void* const* d_in, const int* in_sizes, int n_in,
                              void* d_out, int out_size, void* d_ws, size_t ws_size,
                              hipStream_t stream)
{
    const float* x  = (const float*)d_in[0];
    const float* Wq = (const float*)d_in[1];
    const float* bq = (const float*)d_in[2];
    const float* Wk = (const float*)d_in[3];
    const float* bk = (const float*)d_in[4];
    const float* Wv = (const float*)d_in[5];
    const float* bv = (const float*)d_in[6];
    const float* Wo = (const float*)d_in[7];
    const float* bo = (const float*)d_in[8];
    const float* W1 = (const float*)d_in[9];
    const float* b1 = (const float*)d_in[10];
    const float* W2 = (const float*)d_in[11];
    const float* b2 = (const float*)d_in[12];
    const float* hs = (const float*)d_in[13];

    const size_t WELEM = (size_t)En * En;
    unsigned short* Wcat = (unsigned short*)d_ws;            // 4*WELEM
    unsigned short* W2b  = Wcat + 4 * WELEM;                 // 64*1024
    float* bcat = (float*)(W2b + (size_t)SIGn * HIDn);       // 4096 floats
    float* gate = bcat + 4096;                               // 4096*16 floats
    unsigned short* t1b = (unsigned short*)(gate + (size_t)Mn * Hn);
    unsigned short* qb  = t1b + (size_t)Mn * En;
    unsigned short* kb  = qb  + (size_t)Mn * En;
    unsigned short* vb  = kb  + (size_t)Mn * En;
    unsigned short* xb  = vb  + (size_t)Mn * En;             // optional +8MB
    unsigned short* Wob = Wcat;   // alias
    unsigned short* vtb = t1b;    // alias
    unsigned short* ob  = vb;     // alias

    const size_t need_xb =
        (size_t)((char*)(xb + (size_t)Mn * En) - (char*)d_ws);
    const bool pre = ws_size >= need_xb;   // deterministic: ws_size is fixed

    dim3 blk(256);
    const int castGrid = (int)(WELEM / 8 / 256);

    cast_w4<<<dim3(castGrid, 4), blk, 0, stream>>>(W1, Wq, Wk, Wv, Wcat);
    cast_bf16<<<32, blk, 0, stream>>>(W2, W2b, (int)((size_t)SIGn * HIDn / 8));
    bias_concat<<<16, blk, 0, stream>>>(b1, bq, bk, bv, bcat);

    if (pre) {
        cast_bf16<<<dim3((int)((size_t)Mn * En / 8 / 256)), blk, 0, stream>>>(
            x, xb, (int)((size_t)Mn * En / 8));
        fused_proj<1><<<dim3(32, 32), blk, 0, stream>>>(
            x, xb, Wcat, bcat, t1b, qb, kb, vb);
    } else {
        fused_proj<0><<<dim3(32, 32), blk, 0, stream>>>(
            x, xb, Wcat, bcat, t1b, qb, kb, vb);
    }

    t2gate<<<dim3(Mn / 16), blk, 0, stream>>>(t1b, W2b, b2, hs, gate);

    transpose_v<<<dim3(Bn * Hn, Tn / 64), blk, 0, stream>>>(vb, vtb);

    cast_bf16<<<castGrid, blk, 0, stream>>>(Wo, Wob, (int)(WELEM / 8));

    attn_mfma<<<dim3(Bn * Hn, Tn / 64), blk, 0, stream>>>(qb, kb, vtb, gate, ob);

    out_proj<<<dim3(8, 64), blk, 0, stream>>>(ob, Wob, bo, (float*)d_out);
}